// Round 1
// baseline (1433.732 us; speedup 1.0000x reference)
//
#include <hip/hip_runtime.h>

#define Bn 8
#define Cn 192
#define CRn 64
#define Dn 384
#define Ln 4096
#define Hn 64
#define Wn 64
#define NTOKn 64
#define NSTn 16
#define Rn 24
#define IRn 128
#define CHn 16
#define LCn 256

// ---------------- prep: full_emb = emb_B@emb_A, transpose x_proj_w and out_w
__global__ __launch_bounds__(256) void k_prep(const float* __restrict__ emb_B,
    const float* __restrict__ emb_A, const float* __restrict__ x_proj_w,
    const float* __restrict__ out_w, float* __restrict__ full_emb,
    float* __restrict__ xprojT, float* __restrict__ out_wT) {
  int t = blockIdx.x * 256 + threadIdx.x;
  if (t < NTOKn * NSTn) {
    int tok = t / NSTn, s = t % NSTn;
    float acc = 0.f;
    for (int k = 0; k < IRn; ++k) acc += emb_B[tok * IRn + k] * emb_A[k * NSTn + s];
    full_emb[t] = acc;
  }
  if (t < Dn * 56) {
    int d = t / 56, j = t % 56;
    xprojT[t] = x_proj_w[j * Dn + d];
  }
  if (t < Dn * Cn) {
    int d = t / Cn, c = t % Cn;
    out_wT[t] = out_w[c * Dn + d];
  }
}

// ---------------- routing: idx = argmax over 64 classes of (W2 gelu(W1 x + b1) + b2 + gumbel)
__global__ __launch_bounds__(256) void k_route(const float* __restrict__ x,
    const float* __restrict__ gumbel, const float* __restrict__ w1,
    const float* __restrict__ b1, const float* __restrict__ w2,
    const float* __restrict__ b2, int* __restrict__ idx_out) {
  int b = blockIdx.x >> 4;
  int l = ((blockIdx.x & 15) << 8) + threadIdx.x;
  const float* xb = x + (size_t)b * Cn * Ln + l;
  float h1[CRn];
#pragma unroll
  for (int j = 0; j < CRn; ++j) h1[j] = b1[j];
  for (int c = 0; c < Cn; c += 4) {
    float x0 = xb[(size_t)c * Ln];
    float x1 = xb[(size_t)(c + 1) * Ln];
    float x2 = xb[(size_t)(c + 2) * Ln];
    float x3 = xb[(size_t)(c + 3) * Ln];
#pragma unroll
    for (int j = 0; j < CRn; ++j) {
      const float* wr = w1 + j * Cn + c;
      h1[j] += wr[0] * x0 + wr[1] * x1 + wr[2] * x2 + wr[3] * x3;
    }
  }
#pragma unroll
  for (int j = 0; j < CRn; ++j) {
    float v = h1[j];
    h1[j] = 0.5f * v * (1.f + erff(v * 0.70710678118654752f));  // exact gelu
  }
  const float* gp = gumbel + ((size_t)b * Ln + l) * NTOKn;
  float best = -3.4e38f;
  int bi = 0;
  for (int k = 0; k < NTOKn; ++k) {
    float s = b2[k];
    const float* wr = w2 + k * CRn;
#pragma unroll
    for (int j = 0; j < CRn; ++j) s += wr[j] * h1[j];
    s += gp[k];
    if (s > best) { best = s; bi = k; }  // first-max wins == jnp.argmax
  }
  idx_out[(size_t)b * Ln + l] = bi;
}

// ---------------- stable counting sort (per batch): sort_idx, inv_idx
__global__ __launch_bounds__(64) void k_sort(const int* __restrict__ idx_in,
    int* __restrict__ sidx, int* __restrict__ iidx) {
  __shared__ int idx_l[Ln];
  __shared__ int hist[NTOKn][NTOKn + 1];  // [class][chunk]
  __shared__ int offs[NTOKn][NTOKn + 1];
  __shared__ int sort_l[Ln];
  __shared__ int inv_l[Ln];
  int b = blockIdx.x;
  int lane = threadIdx.x;
  const int* ip = idx_in + (size_t)b * Ln;
  for (int t = lane; t < Ln; t += 64) idx_l[t] = ip[t];
  for (int t = lane; t < NTOKn * (NTOKn + 1); t += 64) (&hist[0][0])[t] = 0;
  __syncthreads();
  {  // phase A: lane = chunk
    int base = lane * 64;
    for (int t = 0; t < 64; ++t) {
      int c = idx_l[base + t];
      hist[c][lane]++;
    }
  }
  __syncthreads();
  {  // phase B: lane = class; exclusive prefix across classes then across chunks
    int tot = 0;
    for (int k = 0; k < 64; ++k) tot += hist[lane][k];
    int incl = tot;
    for (int o = 1; o < 64; o <<= 1) {
      int v = __shfl_up(incl, o, 64);
      if (lane >= o) incl += v;
    }
    int run = incl - tot;
    for (int k = 0; k < 64; ++k) { offs[lane][k] = run; run += hist[lane][k]; }
  }
  __syncthreads();
  {  // phase C: lane = chunk, stable within chunk
    int base = lane * 64;
    for (int t = 0; t < 64; ++t) {
      int gl = base + t;
      int c = idx_l[gl];
      int p = offs[c][lane]++;
      sort_l[p] = gl;
      inv_l[gl] = p;
    }
  }
  __syncthreads();
  for (int t = lane; t < Ln; t += 64) {
    sidx[(size_t)b * Ln + t] = sort_l[t];
    iidx[(size_t)b * Ln + t] = inv_l[t];
  }
}

// ---------------- in_proj: v0[b,d,l] = sum_c W[d,c] x[b,c,l] + bias[d]
__global__ __launch_bounds__(256) void k_inproj(const float* __restrict__ x,
    const float* __restrict__ w, const float* __restrict__ bias,
    float* __restrict__ v0) {
  int gid = blockIdx.x;
  int g = gid % 6;
  int lt = (gid / 6) % 16;
  int b = gid / 96;
  int l = lt * 256 + threadIdx.x;
  int d0 = g * 64;
  const float* xb = x + (size_t)b * Cn * Ln + l;
  float acc[64];
#pragma unroll
  for (int dd = 0; dd < 64; ++dd) acc[dd] = bias[d0 + dd];
  for (int c = 0; c < Cn; c += 4) {
    float x0 = xb[(size_t)c * Ln];
    float x1 = xb[(size_t)(c + 1) * Ln];
    float x2 = xb[(size_t)(c + 2) * Ln];
    float x3 = xb[(size_t)(c + 3) * Ln];
#pragma unroll
    for (int dd = 0; dd < 64; ++dd) {
      const float* wr = w + (d0 + dd) * Cn + c;
      acc[dd] += wr[0] * x0 + wr[1] * x1 + wr[2] * x2 + wr[3] * x3;
    }
  }
  float* vp = v0 + ((size_t)b * Dn + d0) * Ln + l;
#pragma unroll
  for (int dd = 0; dd < 64; ++dd) vp[(size_t)dd * Ln] = acc[dd];
}

// ---------------- depthwise 3x3 SAME conv + sigmoid gate
__global__ __launch_bounds__(256) void k_cpe(const float* __restrict__ v0,
    const float* __restrict__ cw, const float* __restrict__ cb,
    float* __restrict__ v) {
  int b = blockIdx.x / Dn;
  int d = blockIdx.x % Dn;
  __shared__ float plane[Hn][Wn + 1];
  const float* src = v0 + ((size_t)b * Dn + d) * Ln;
  float* dst = v + ((size_t)b * Dn + d) * Ln;
  for (int i = threadIdx.x; i < Ln; i += 256) plane[i >> 6][i & 63] = src[i];
  float kw[9];
#pragma unroll
  for (int k = 0; k < 9; ++k) kw[k] = cw[d * 9 + k];
  float bb = cb[d];
  __syncthreads();
  for (int i = threadIdx.x; i < Ln; i += 256) {
    int y = i >> 6, xx = i & 63;
    float s = bb;
#pragma unroll
    for (int ky = 0; ky < 3; ++ky) {
      int yy = y + ky - 1;
      if (yy < 0 || yy >= Hn) continue;
#pragma unroll
      for (int kx = 0; kx < 3; ++kx) {
        int x2 = xx + kx - 1;
        if (x2 < 0 || x2 >= Wn) continue;
        s += plane[yy][x2] * kw[ky * 3 + kx];
      }
    }
    float g = 1.f / (1.f + expf(-s));
    dst[i] = plane[y][xx] * g;
  }
}

// ---------------- gather u[b,d,i] = v[b,d,sidx[b,i]]
__global__ __launch_bounds__(256) void k_gather(const float* __restrict__ v,
    const int* __restrict__ sidx, float* __restrict__ u) {
  int b = blockIdx.x >> 6;
  int it = blockIdx.x & 63;
  int i = it * 64 + (threadIdx.x & 63);
  int q = threadIdx.x >> 6;
  int sj = sidx[(size_t)b * Ln + i];
  const float* vb = v + (size_t)b * Dn * Ln;
  float* ub = u + (size_t)b * Dn * Ln;
  for (int dc = 0; dc < Dn / 4; ++dc) {
    int d = dc * 4 + q;
    ub[(size_t)d * Ln + i] = vb[(size_t)d * Ln + sj];
  }
}

// ---------------- x_dbl[b,j,i] = sum_d x_proj_w[j,d] u[b,d,i]  (+ full_emb[idx] on Cs rows)
__global__ __launch_bounds__(256) void k_xdbl(const float* __restrict__ u,
    const float* __restrict__ xprojT, const float* __restrict__ femb,
    const int* __restrict__ idx_in, float* __restrict__ xdbl) {
  int gid = blockIdx.x;
  int jg = gid & 1;
  int lt = (gid >> 1) & 15;
  int b = gid >> 5;
  int i = lt * 256 + threadIdx.x;
  int j0 = jg * 28;
  const float* ub = u + (size_t)b * Dn * Ln + i;
  float acc[28];
#pragma unroll
  for (int jj = 0; jj < 28; ++jj) acc[jj] = 0.f;
  for (int d = 0; d < Dn; ++d) {
    float uv = ub[(size_t)d * Ln];
    const float* wr = xprojT + d * 56 + j0;
#pragma unroll
    for (int jj = 0; jj < 28; ++jj) acc[jj] += wr[jj] * uv;
  }
  int cls = idx_in[(size_t)b * Ln + i];  // ORIGINAL-order idx (reference adds prompt unsorted)
  float* op = xdbl + ((size_t)b * 56 + j0) * Ln + i;
#pragma unroll
  for (int jj = 0; jj < 28; ++jj) {
    int j = j0 + jj;
    float val = acc[jj];
    if (j >= 40) val += femb[cls * NSTn + (j - 40)];
    op[(size_t)jj * Ln] = val;
  }
}

// ---------------- delta = softplus(dt_w @ dts + dt_b)
__global__ __launch_bounds__(256) void k_delta(const float* __restrict__ xdbl,
    const float* __restrict__ dt_w, const float* __restrict__ dt_b,
    float* __restrict__ delta) {
  int gid = blockIdx.x;
  int g = gid % 6;
  int lt = (gid / 6) % 16;
  int b = gid / 96;
  int i = lt * 256 + threadIdx.x;
  int d0 = g * 64;
  const float* tp = xdbl + (size_t)b * 56 * Ln + i;
  float acc[64];
#pragma unroll
  for (int dd = 0; dd < 64; ++dd) acc[dd] = dt_b[d0 + dd];
  for (int r = 0; r < Rn; ++r) {
    float tv = tp[(size_t)r * Ln];
#pragma unroll
    for (int dd = 0; dd < 64; ++dd) acc[dd] += dt_w[(d0 + dd) * Rn + r] * tv;
  }
  float* op = delta + ((size_t)b * Dn + d0) * Ln + i;
#pragma unroll
  for (int dd = 0; dd < 64; ++dd) {
    float s = acc[dd];
    op[(size_t)dd * Ln] = fmaxf(s, 0.f) + log1pf(expf(-fabsf(s)));
  }
}

// ---------------- scan phase 1: per-chunk (prod a, h-from-zero)
__global__ __launch_bounds__(256) void k_scan1(const float* __restrict__ delta,
    const float* __restrict__ u, const float* __restrict__ xdbl,
    const float* __restrict__ A_logs, float* __restrict__ aprod_o,
    float* __restrict__ hacc_o) {
  int gid = blockIdx.x;
  int dg = gid % 24;
  int ck = (gid / 24) % CHn;
  int b = gid / 384;
  int tid = threadIdx.x;
  int n = tid & 15;
  int d = dg * 16 + (tid >> 4);
  float Av = -expf(A_logs[d * NSTn + n]);
  const float* dp = delta + ((size_t)b * Dn + d) * Ln + ck * LCn;
  const float* up = u + ((size_t)b * Dn + d) * Ln + ck * LCn;
  const float* bp = xdbl + ((size_t)b * 56 + 24 + n) * Ln + ck * LCn;
  float ap = 1.f, hc = 0.f;
  for (int t = 0; t < LCn; t += 4) {
    float4 d4 = *(const float4*)(dp + t);
    float4 u4 = *(const float4*)(up + t);
    float4 b4 = *(const float4*)(bp + t);
    float dv[4] = {d4.x, d4.y, d4.z, d4.w};
    float uv[4] = {u4.x, u4.y, u4.z, u4.w};
    float bv[4] = {b4.x, b4.y, b4.z, b4.w};
#pragma unroll
    for (int q = 0; q < 4; ++q) {
      float a = __expf(dv[q] * Av);
      hc = hc * a + dv[q] * uv[q] * bv[q];
      ap *= a;
    }
  }
  size_t o = ((size_t)(b * CHn + ck) * Dn + dg * 16) * NSTn + tid;
  aprod_o[o] = ap;
  hacc_o[o] = hc;
}

// ---------------- scan phase 2: combine chunks sequentially (16 steps)
__global__ __launch_bounds__(256) void k_scan2(const float* __restrict__ aprod,
    const float* __restrict__ hacc, float* __restrict__ hstart) {
  int gid = blockIdx.x * 256 + threadIdx.x;  // over B*D*NST
  int b = gid / (Dn * NSTn);
  int dn = gid % (Dn * NSTn);
  float h = 0.f;
  for (int k = 0; k < CHn; ++k) {
    size_t o = (size_t)(b * CHn + k) * Dn * NSTn + dn;
    hstart[o] = h;
    h = h * aprod[o] + hacc[o];
  }
}

// ---------------- scan phase 3: replay with h_start, emit y (+Ds*u)
__global__ __launch_bounds__(256) void k_scan3(const float* __restrict__ delta,
    const float* __restrict__ u, const float* __restrict__ xdbl,
    const float* __restrict__ A_logs, const float* __restrict__ Ds,
    const float* __restrict__ hstart, float* __restrict__ ys) {
  int gid = blockIdx.x;
  int dg = gid % 24;
  int ck = (gid / 24) % CHn;
  int b = gid / 384;
  int tid = threadIdx.x;
  int n = tid & 15;
  int dloc = tid >> 4;
  int d = dg * 16 + dloc;
  float Av = -expf(A_logs[d * NSTn + n]);
  float Dv = Ds[d];
  const float* dp = delta + ((size_t)b * Dn + d) * Ln + ck * LCn;
  const float* up = u + ((size_t)b * Dn + d) * Ln + ck * LCn;
  const float* bp = xdbl + ((size_t)b * 56 + 24 + n) * Ln + ck * LCn;
  const float* cp = xdbl + ((size_t)b * 56 + 40 + n) * Ln + ck * LCn;
  float h = hstart[((size_t)(b * CHn + ck) * Dn + dg * 16) * NSTn + tid];
  __shared__ float ylds[64][17];
  for (int t64 = 0; t64 < LCn / 64; ++t64) {
    for (int t = 0; t < 64; t += 4) {
      int tt = t64 * 64 + t;
      float4 d4 = *(const float4*)(dp + tt);
      float4 u4 = *(const float4*)(up + tt);
      float4 b4 = *(const float4*)(bp + tt);
      float4 c4 = *(const float4*)(cp + tt);
      float dv[4] = {d4.x, d4.y, d4.z, d4.w};
      float uv[4] = {u4.x, u4.y, u4.z, u4.w};
      float bv[4] = {b4.x, b4.y, b4.z, b4.w};
      float cv[4] = {c4.x, c4.y, c4.z, c4.w};
#pragma unroll
      for (int q = 0; q < 4; ++q) {
        float a = __expf(dv[q] * Av);
        h = h * a + dv[q] * uv[q] * bv[q];
        float p = h * cv[q];
        p += __shfl_xor(p, 8, 16);
        p += __shfl_xor(p, 4, 16);
        p += __shfl_xor(p, 2, 16);
        p += __shfl_xor(p, 1, 16);
        if (n == 0) ylds[t + q][dloc] = p + Dv * uv[q];
      }
    }
    __syncthreads();
    int i0 = ck * LCn + t64 * 64;
    for (int e = tid; e < 64 * 16; e += 256) {
      int ii = e >> 4, dd = e & 15;
      ys[((size_t)b * Ln + i0 + ii) * Dn + dg * 16 + dd] = ylds[ii][dd];
    }
    __syncthreads();
  }
}

// ---------------- layernorm + out projection (sorted domain)
__global__ __launch_bounds__(256) void k_lnproj(const float* __restrict__ ys,
    const float* __restrict__ ln_g, const float* __restrict__ ln_b,
    const float* __restrict__ out_wT, const float* __restrict__ out_b,
    float* __restrict__ outs) {
  int b = blockIdx.x >> 6;
  int it = blockIdx.x & 63;
  int i0 = it * 64;
  __shared__ float yt[64][385];
  __shared__ float ps[64][4];
  __shared__ float pq[64][4];
  __shared__ float smu[64];
  __shared__ float srs[64];
  const float* src = ys + ((size_t)b * Ln + i0) * Dn;
  for (int e = threadIdx.x; e < 6144; e += 256) {
    int tok = e / 96;
    int dq = (e % 96) * 4;
    float4 vv = *(const float4*)(src + (size_t)tok * Dn + dq);
    yt[tok][dq] = vv.x;
    yt[tok][dq + 1] = vv.y;
    yt[tok][dq + 2] = vv.z;
    yt[tok][dq + 3] = vv.w;
  }
  __syncthreads();
  int tok = threadIdx.x & 63, prt = threadIdx.x >> 6;
  {
    float s = 0.f, sq = 0.f;
    for (int d = prt * 96; d < prt * 96 + 96; ++d) {
      float v = yt[tok][d];
      s += v;
      sq += v * v;
    }
    ps[tok][prt] = s;
    pq[tok][prt] = sq;
  }
  __syncthreads();
  if (threadIdx.x < 64) {
    int tk = threadIdx.x;
    float s = ps[tk][0] + ps[tk][1] + ps[tk][2] + ps[tk][3];
    float q = pq[tk][0] + pq[tk][1] + pq[tk][2] + pq[tk][3];
    float mu = s * (1.f / Dn);
    float var = q * (1.f / Dn) - mu * mu;
    smu[tk] = mu;
    srs[tk] = rsqrtf(var + 1e-5f);
  }
  __syncthreads();
  for (int e = threadIdx.x; e < 64 * Dn; e += 256) {
    int tk = e / Dn;
    int d = e % Dn;
    float v = yt[tk][d];
    yt[tk][d] = (v - smu[tk]) * srs[tk] * ln_g[d] + ln_b[d];
  }
  __syncthreads();
  int cg = threadIdx.x >> 6;
  int c0 = cg * 48;
  float acc[48];
#pragma unroll
  for (int j = 0; j < 48; ++j) acc[j] = out_b[c0 + j];
  for (int d = 0; d < Dn; ++d) {
    float yv = yt[tok][d];
    const float* wr = out_wT + d * Cn + c0;
#pragma unroll
    for (int j = 0; j < 48; ++j) acc[j] += wr[j] * yv;
  }
  float* op = outs + ((size_t)b * Ln + i0 + tok) * Cn + c0;
#pragma unroll
  for (int j = 0; j < 48; ++j) op[j] = acc[j];
}

// ---------------- inverse-permute + transpose to (B, C, L)
__global__ __launch_bounds__(256) void k_perm(const float* __restrict__ outs,
    const int* __restrict__ iidx, float* __restrict__ out) {
  int b = blockIdx.x >> 6;
  int lt = blockIdx.x & 63;
  int l0 = lt * 64;
  __shared__ float ot[64][Cn + 1];
  __shared__ int ivs[64];
  if (threadIdx.x < 64) ivs[threadIdx.x] = iidx[(size_t)b * Ln + l0 + threadIdx.x];
  __syncthreads();
  for (int e = threadIdx.x; e < 3072; e += 256) {
    int ii = e / 48;
    int qq = (e % 48) * 4;
    const float* sp = outs + ((size_t)b * Ln + ivs[ii]) * Cn + qq;
    float4 vv = *(const float4*)sp;
    ot[ii][qq] = vv.x;
    ot[ii][qq + 1] = vv.y;
    ot[ii][qq + 2] = vv.z;
    ot[ii][qq + 3] = vv.w;
  }
  __syncthreads();
  for (int e = threadIdx.x; e < 64 * Cn; e += 256) {
    int c = e >> 6;
    int ii = e & 63;
    out[((size_t)b * Cn + c) * Ln + l0 + ii] = ot[ii][c];
  }
}

extern "C" void kernel_launch(void* const* d_in, const int* in_sizes, int n_in,
                              void* d_out, int out_size, void* d_ws, size_t ws_size,
                              hipStream_t stream) {
  (void)in_sizes; (void)n_in; (void)out_size; (void)ws_size;
  const float* x = (const float*)d_in[0];
  const float* gumbel = (const float*)d_in[1];
  const float* emb_B = (const float*)d_in[2];
  const float* emb_A = (const float*)d_in[3];
  const float* route_w1 = (const float*)d_in[4];
  const float* route_b1 = (const float*)d_in[5];
  const float* route_w2 = (const float*)d_in[6];
  const float* route_b2 = (const float*)d_in[7];
  const float* in_proj_w = (const float*)d_in[8];
  const float* in_proj_b = (const float*)d_in[9];
  const float* cpe_w = (const float*)d_in[10];
  const float* cpe_b = (const float*)d_in[11];
  const float* x_proj_w = (const float*)d_in[12];
  const float* dt_w = (const float*)d_in[13];
  const float* dt_b = (const float*)d_in[14];
  const float* A_logs = (const float*)d_in[15];
  const float* Ds = (const float*)d_in[16];
  const float* ln_g = (const float*)d_in[17];
  const float* ln_b = (const float*)d_in[18];
  const float* out_w = (const float*)d_in[19];
  const float* out_b = (const float*)d_in[20];

  float* ws = (float*)d_ws;
  float* v0 = ws;                     // 12582912 (later ys)
  float* v = v0 + 12582912;           // 12582912 (later out_sorted)
  float* u = v + 12582912;            // 12582912
  float* dl = u + 12582912;           // 12582912
  float* xd = dl + 12582912;          // 1835008
  float* ap = xd + 1835008;           // 786432
  float* hc = ap + 786432;            // 786432
  float* hs = hc + 786432;            // 786432
  float* fe = hs + 786432;            // 1024
  float* owT = fe + 1024;             // 73728
  float* xpT = owT + 73728;           // 21504
  int* idxp = (int*)(xpT + 21504);    // 32768
  int* sidx = idxp + 32768;           // 32768
  int* iidx = sidx + 32768;           // 32768  -> total ~219 MB

  k_prep<<<288, 256, 0, stream>>>(emb_B, emb_A, x_proj_w, out_w, fe, xpT, owT);
  k_route<<<128, 256, 0, stream>>>(x, gumbel, route_w1, route_b1, route_w2, route_b2, idxp);
  k_sort<<<8, 64, 0, stream>>>(idxp, sidx, iidx);
  k_inproj<<<768, 256, 0, stream>>>(x, in_proj_w, in_proj_b, v0);
  k_cpe<<<Bn * Dn, 256, 0, stream>>>(v0, cpe_w, cpe_b, v);
  k_gather<<<512, 256, 0, stream>>>(v, sidx, u);
  k_xdbl<<<256, 256, 0, stream>>>(u, xpT, fe, idxp, xd);
  k_delta<<<768, 256, 0, stream>>>(xd, dt_w, dt_b, dl);
  k_scan1<<<3072, 256, 0, stream>>>(dl, u, xd, A_logs, ap, hc);
  k_scan2<<<192, 256, 0, stream>>>(ap, hc, hs);
  k_scan3<<<3072, 256, 0, stream>>>(dl, u, xd, A_logs, Ds, hs, v0);
  k_lnproj<<<512, 256, 0, stream>>>(v0, ln_g, ln_b, owT, out_b, v);
  k_perm<<<512, 256, 0, stream>>>(v, iidx, (float*)d_out);
}

// Round 2
// 1277.798 us; speedup vs baseline: 1.1220x; 1.1220x over previous
//
#include <hip/hip_runtime.h>

#define Bn 8
#define Cn 192
#define CRn 64
#define Dn 384
#define Ln 4096
#define Hn 64
#define Wn 64
#define NTOKn 64
#define NSTn 16
#define Rn 24
#define IRn 128
#define CHn 16
#define LCn 256

// ---------------- prep: full_emb = emb_B@emb_A, transpose x_proj_w and out_w
__global__ __launch_bounds__(256) void k_prep(const float* __restrict__ emb_B,
    const float* __restrict__ emb_A, const float* __restrict__ x_proj_w,
    const float* __restrict__ out_w, float* __restrict__ full_emb,
    float* __restrict__ xprojT, float* __restrict__ out_wT) {
  int t = blockIdx.x * 256 + threadIdx.x;
  if (t < NTOKn * NSTn) {
    int tok = t / NSTn, s = t % NSTn;
    float acc = 0.f;
    for (int k = 0; k < IRn; ++k) acc += emb_B[tok * IRn + k] * emb_A[k * NSTn + s];
    full_emb[t] = acc;
  }
  if (t < Dn * 56) {
    int d = t / 56, j = t % 56;
    xprojT[t] = x_proj_w[j * Dn + d];
  }
  if (t < Dn * Cn) {
    int d = t / Cn, c = t % Cn;
    out_wT[t] = out_w[c * Dn + d];
  }
}

// ---------------- routing: idx = argmax over 64 classes of (W2 gelu(W1 x + b1) + b2 + gumbel)
__global__ __launch_bounds__(256) void k_route(const float* __restrict__ x,
    const float* __restrict__ gumbel, const float* __restrict__ w1,
    const float* __restrict__ b1, const float* __restrict__ w2,
    const float* __restrict__ b2, int* __restrict__ idx_out) {
  int b = blockIdx.x >> 4;
  int l = ((blockIdx.x & 15) << 8) + threadIdx.x;
  const float* xb = x + (size_t)b * Cn * Ln + l;
  float h1[CRn];
#pragma unroll
  for (int j = 0; j < CRn; ++j) h1[j] = b1[j];
  for (int c = 0; c < Cn; c += 4) {
    float x0 = xb[(size_t)c * Ln];
    float x1 = xb[(size_t)(c + 1) * Ln];
    float x2 = xb[(size_t)(c + 2) * Ln];
    float x3 = xb[(size_t)(c + 3) * Ln];
#pragma unroll
    for (int j = 0; j < CRn; ++j) {
      const float* wr = w1 + j * Cn + c;
      h1[j] += wr[0] * x0 + wr[1] * x1 + wr[2] * x2 + wr[3] * x3;
    }
  }
#pragma unroll
  for (int j = 0; j < CRn; ++j) {
    float v = h1[j];
    h1[j] = 0.5f * v * (1.f + erff(v * 0.70710678118654752f));  // exact gelu
  }
  const float* gp = gumbel + ((size_t)b * Ln + l) * NTOKn;
  float best = -3.4e38f;
  int bi = 0;
  for (int k = 0; k < NTOKn; ++k) {
    float s = b2[k];
    const float* wr = w2 + k * CRn;
#pragma unroll
    for (int j = 0; j < CRn; ++j) s += wr[j] * h1[j];
    s += gp[k];
    if (s > best) { best = s; bi = k; }  // first-max wins == jnp.argmax
  }
  idx_out[(size_t)b * Ln + l] = bi;
}

// ---------------- stable counting sort (per batch): sort_idx, inv_idx
__global__ __launch_bounds__(64) void k_sort(const int* __restrict__ idx_in,
    int* __restrict__ sidx, int* __restrict__ iidx) {
  __shared__ int idx_l[Ln];
  __shared__ int hist[NTOKn][NTOKn + 1];  // [class][chunk]
  __shared__ int offs[NTOKn][NTOKn + 1];
  __shared__ int sort_l[Ln];
  __shared__ int inv_l[Ln];
  int b = blockIdx.x;
  int lane = threadIdx.x;
  const int* ip = idx_in + (size_t)b * Ln;
  for (int t = lane; t < Ln; t += 64) idx_l[t] = ip[t];
  for (int t = lane; t < NTOKn * (NTOKn + 1); t += 64) (&hist[0][0])[t] = 0;
  __syncthreads();
  {  // phase A: lane = chunk
    int base = lane * 64;
    for (int t = 0; t < 64; ++t) {
      int c = idx_l[base + t];
      hist[c][lane]++;
    }
  }
  __syncthreads();
  {  // phase B: lane = class; exclusive prefix across classes then across chunks
    int tot = 0;
    for (int k = 0; k < 64; ++k) tot += hist[lane][k];
    int incl = tot;
    for (int o = 1; o < 64; o <<= 1) {
      int v = __shfl_up(incl, o, 64);
      if (lane >= o) incl += v;
    }
    int run = incl - tot;
    for (int k = 0; k < 64; ++k) { offs[lane][k] = run; run += hist[lane][k]; }
  }
  __syncthreads();
  {  // phase C: lane = chunk, stable within chunk
    int base = lane * 64;
    for (int t = 0; t < 64; ++t) {
      int gl = base + t;
      int c = idx_l[gl];
      int p = offs[c][lane]++;
      sort_l[p] = gl;
      inv_l[gl] = p;
    }
  }
  __syncthreads();
  for (int t = lane; t < Ln; t += 64) {
    sidx[(size_t)b * Ln + t] = sort_l[t];
    iidx[(size_t)b * Ln + t] = inv_l[t];
  }
}

// ---------------- in_proj: v0[b,d,l] = sum_c W[d,c] x[b,c,l] + bias[d]
__global__ __launch_bounds__(256) void k_inproj(const float* __restrict__ x,
    const float* __restrict__ w, const float* __restrict__ bias,
    float* __restrict__ v0) {
  int gid = blockIdx.x;
  int g = gid % 6;
  int lt = (gid / 6) % 16;
  int b = gid / 96;
  int l = lt * 256 + threadIdx.x;
  int d0 = g * 64;
  const float* xb = x + (size_t)b * Cn * Ln + l;
  float acc[64];
#pragma unroll
  for (int dd = 0; dd < 64; ++dd) acc[dd] = bias[d0 + dd];
  for (int c = 0; c < Cn; c += 4) {
    float x0 = xb[(size_t)c * Ln];
    float x1 = xb[(size_t)(c + 1) * Ln];
    float x2 = xb[(size_t)(c + 2) * Ln];
    float x3 = xb[(size_t)(c + 3) * Ln];
#pragma unroll
    for (int dd = 0; dd < 64; ++dd) {
      const float* wr = w + (d0 + dd) * Cn + c;
      acc[dd] += wr[0] * x0 + wr[1] * x1 + wr[2] * x2 + wr[3] * x3;
    }
  }
  float* vp = v0 + ((size_t)b * Dn + d0) * Ln + l;
#pragma unroll
  for (int dd = 0; dd < 64; ++dd) vp[(size_t)dd * Ln] = acc[dd];
}

// ---------------- depthwise 3x3 SAME conv + sigmoid gate
__global__ __launch_bounds__(256) void k_cpe(const float* __restrict__ v0,
    const float* __restrict__ cw, const float* __restrict__ cb,
    float* __restrict__ v) {
  int b = blockIdx.x / Dn;
  int d = blockIdx.x % Dn;
  __shared__ float plane[Hn][Wn + 1];
  const float* src = v0 + ((size_t)b * Dn + d) * Ln;
  float* dst = v + ((size_t)b * Dn + d) * Ln;
  for (int i = threadIdx.x; i < Ln; i += 256) plane[i >> 6][i & 63] = src[i];
  float kw[9];
#pragma unroll
  for (int k = 0; k < 9; ++k) kw[k] = cw[d * 9 + k];
  float bb = cb[d];
  __syncthreads();
  for (int i = threadIdx.x; i < Ln; i += 256) {
    int y = i >> 6, xx = i & 63;
    float s = bb;
#pragma unroll
    for (int ky = 0; ky < 3; ++ky) {
      int yy = y + ky - 1;
      if (yy < 0 || yy >= Hn) continue;
#pragma unroll
      for (int kx = 0; kx < 3; ++kx) {
        int x2 = xx + kx - 1;
        if (x2 < 0 || x2 >= Wn) continue;
        s += plane[yy][x2] * kw[ky * 3 + kx];
      }
    }
    float g = 1.f / (1.f + expf(-s));
    dst[i] = plane[y][xx] * g;
  }
}

// ---------------- gather u[b,d,i] = v[b,d,sidx[b,i]]
__global__ __launch_bounds__(256) void k_gather(const float* __restrict__ v,
    const int* __restrict__ sidx, float* __restrict__ u) {
  int b = blockIdx.x >> 6;
  int it = blockIdx.x & 63;
  int i = it * 64 + (threadIdx.x & 63);
  int q = threadIdx.x >> 6;
  int sj = sidx[(size_t)b * Ln + i];
  const float* vb = v + (size_t)b * Dn * Ln;
  float* ub = u + (size_t)b * Dn * Ln;
  for (int dc = 0; dc < Dn / 4; ++dc) {
    int d = dc * 4 + q;
    ub[(size_t)d * Ln + i] = vb[(size_t)d * Ln + sj];
  }
}

// ---------------- x_dbl[b,j,i] = sum_d x_proj_w[j,d] u[b,d,i]  (+ full_emb[idx] on Cs rows)
__global__ __launch_bounds__(256) void k_xdbl(const float* __restrict__ u,
    const float* __restrict__ xprojT, const float* __restrict__ femb,
    const int* __restrict__ idx_in, float* __restrict__ xdbl) {
  int gid = blockIdx.x;
  int jg = gid & 1;
  int lt = (gid >> 1) & 15;
  int b = gid >> 5;
  int i = lt * 256 + threadIdx.x;
  int j0 = jg * 28;
  const float* ub = u + (size_t)b * Dn * Ln + i;
  float acc[28];
#pragma unroll
  for (int jj = 0; jj < 28; ++jj) acc[jj] = 0.f;
  for (int d = 0; d < Dn; ++d) {
    float uv = ub[(size_t)d * Ln];
    const float* wr = xprojT + d * 56 + j0;
#pragma unroll
    for (int jj = 0; jj < 28; ++jj) acc[jj] += wr[jj] * uv;
  }
  int cls = idx_in[(size_t)b * Ln + i];  // ORIGINAL-order idx (reference adds prompt unsorted)
  float* op = xdbl + ((size_t)b * 56 + j0) * Ln + i;
#pragma unroll
  for (int jj = 0; jj < 28; ++jj) {
    int j = j0 + jj;
    float val = acc[jj];
    if (j >= 40) val += femb[cls * NSTn + (j - 40)];
    op[(size_t)jj * Ln] = val;
  }
}

// ---------------- delta = softplus(dt_w @ dts + dt_b)
__global__ __launch_bounds__(256) void k_delta(const float* __restrict__ xdbl,
    const float* __restrict__ dt_w, const float* __restrict__ dt_b,
    float* __restrict__ delta) {
  int gid = blockIdx.x;
  int g = gid % 6;
  int lt = (gid / 6) % 16;
  int b = gid / 96;
  int i = lt * 256 + threadIdx.x;
  int d0 = g * 64;
  const float* tp = xdbl + (size_t)b * 56 * Ln + i;
  float acc[64];
#pragma unroll
  for (int dd = 0; dd < 64; ++dd) acc[dd] = dt_b[d0 + dd];
  for (int r = 0; r < Rn; ++r) {
    float tv = tp[(size_t)r * Ln];
#pragma unroll
    for (int dd = 0; dd < 64; ++dd) acc[dd] += dt_w[(d0 + dd) * Rn + r] * tv;
  }
  float* op = delta + ((size_t)b * Dn + d0) * Ln + i;
#pragma unroll
  for (int dd = 0; dd < 64; ++dd) {
    float s = acc[dd];
    op[(size_t)dd * Ln] = fmaxf(s, 0.f) + log1pf(expf(-fabsf(s)));
  }
}

// ---------------- scan phase 1: per-chunk (prod a, h-from-zero)
__global__ __launch_bounds__(256) void k_scan1(const float* __restrict__ delta,
    const float* __restrict__ u, const float* __restrict__ xdbl,
    const float* __restrict__ A_logs, float* __restrict__ aprod_o,
    float* __restrict__ hacc_o) {
  int gid = blockIdx.x;
  int dg = gid % 24;
  int ck = (gid / 24) % CHn;
  int b = gid / 384;
  int tid = threadIdx.x;
  int n = tid & 15;
  int d = dg * 16 + (tid >> 4);
  float Av = -expf(A_logs[d * NSTn + n]);
  const float* dp = delta + ((size_t)b * Dn + d) * Ln + ck * LCn;
  const float* up = u + ((size_t)b * Dn + d) * Ln + ck * LCn;
  const float* bp = xdbl + ((size_t)b * 56 + 24 + n) * Ln + ck * LCn;
  float ap = 1.f, hc = 0.f;
  for (int t = 0; t < LCn; t += 4) {
    float4 d4 = *(const float4*)(dp + t);
    float4 u4 = *(const float4*)(up + t);
    float4 b4 = *(const float4*)(bp + t);
    float dv[4] = {d4.x, d4.y, d4.z, d4.w};
    float uv[4] = {u4.x, u4.y, u4.z, u4.w};
    float bv[4] = {b4.x, b4.y, b4.z, b4.w};
#pragma unroll
    for (int q = 0; q < 4; ++q) {
      float a = __expf(dv[q] * Av);
      hc = hc * a + dv[q] * uv[q] * bv[q];
      ap *= a;
    }
  }
  size_t o = ((size_t)(b * CHn + ck) * Dn + dg * 16) * NSTn + tid;
  aprod_o[o] = ap;
  hacc_o[o] = hc;
}

// ---------------- scan phase 2: combine chunks sequentially (16 steps)
__global__ __launch_bounds__(256) void k_scan2(const float* __restrict__ aprod,
    const float* __restrict__ hacc, float* __restrict__ hstart) {
  int gid = blockIdx.x * 256 + threadIdx.x;  // over B*D*NST
  int b = gid / (Dn * NSTn);
  int dn = gid % (Dn * NSTn);
  float h = 0.f;
  for (int k = 0; k < CHn; ++k) {
    size_t o = (size_t)(b * CHn + k) * Dn * NSTn + dn;
    hstart[o] = h;
    h = h * aprod[o] + hacc[o];
  }
}

// ---------------- scan phase 3: replay with h_start, emit y (+Ds*u) in (B,D,L) layout
__global__ __launch_bounds__(256) void k_scan3(const float* __restrict__ delta,
    const float* __restrict__ u, const float* __restrict__ xdbl,
    const float* __restrict__ A_logs, const float* __restrict__ Ds,
    const float* __restrict__ hstart, float* __restrict__ ys) {
  int gid = blockIdx.x;
  int dg = gid % 24;
  int ck = (gid / 24) % CHn;
  int b = gid / 384;
  int tid = threadIdx.x;
  int n = tid & 15;
  int dloc = tid >> 4;
  int d = dg * 16 + dloc;
  float Av = -expf(A_logs[d * NSTn + n]);
  float Dv = Ds[d];
  const float* dp = delta + ((size_t)b * Dn + d) * Ln + ck * LCn;
  const float* up = u + ((size_t)b * Dn + d) * Ln + ck * LCn;
  const float* bp = xdbl + ((size_t)b * 56 + 24 + n) * Ln + ck * LCn;
  const float* cp = xdbl + ((size_t)b * 56 + 40 + n) * Ln + ck * LCn;
  float h = hstart[((size_t)(b * CHn + ck) * Dn + dg * 16) * NSTn + tid];
  __shared__ float ylds[16][65];
  for (int t64 = 0; t64 < LCn / 64; ++t64) {
    for (int t = 0; t < 64; t += 4) {
      int tt = t64 * 64 + t;
      float4 d4 = *(const float4*)(dp + tt);
      float4 u4 = *(const float4*)(up + tt);
      float4 b4 = *(const float4*)(bp + tt);
      float4 c4 = *(const float4*)(cp + tt);
      float dv[4] = {d4.x, d4.y, d4.z, d4.w};
      float uv[4] = {u4.x, u4.y, u4.z, u4.w};
      float bv[4] = {b4.x, b4.y, b4.z, b4.w};
      float cv[4] = {c4.x, c4.y, c4.z, c4.w};
#pragma unroll
      for (int q = 0; q < 4; ++q) {
        float a = __expf(dv[q] * Av);
        h = h * a + dv[q] * uv[q] * bv[q];
        float p = h * cv[q];
        p += __shfl_xor(p, 8, 16);
        p += __shfl_xor(p, 4, 16);
        p += __shfl_xor(p, 2, 16);
        p += __shfl_xor(p, 1, 16);
        if (n == 0) ylds[dloc][t + q] = p + Dv * uv[q];
      }
    }
    __syncthreads();
    int i0 = ck * LCn + t64 * 64;
    for (int e = tid; e < 16 * 64; e += 256) {
      int dd = e >> 6, tt = e & 63;
      ys[((size_t)b * Dn + dg * 16 + dd) * Ln + i0 + tt] = ylds[dd][tt];
    }
    __syncthreads();
  }
}

// ---------------- LN stats per sorted token: mu, rsigma  (ys in (B,D,L))
__global__ __launch_bounds__(256) void k_ln(const float* __restrict__ ys,
    float* __restrict__ mu_o, float* __restrict__ rs_o) {
  int b = blockIdx.x >> 5;
  int i0 = (blockIdx.x & 31) << 7;
  int t = threadIdx.x & 127;
  int half = threadIdx.x >> 7;
  int i = i0 + t;
  const float* p = ys + ((size_t)b * Dn + half * 192) * Ln + i;
  float s = 0.f, q = 0.f;
  for (int d = 0; d < 192; d += 2) {
    float v0 = p[(size_t)d * Ln];
    float v1 = p[(size_t)(d + 1) * Ln];
    s += v0 + v1;
    q += v0 * v0 + v1 * v1;
  }
  __shared__ float sh_s[2][128], sh_q[2][128];
  sh_s[half][t] = s;
  sh_q[half][t] = q;
  __syncthreads();
  if (half == 0) {
    float ts = s + sh_s[1][t];
    float tq = q + sh_q[1][t];
    float mu = ts * (1.f / Dn);
    float var = tq * (1.f / Dn) - mu * mu;
    mu_o[b * Ln + i] = mu;
    rs_o[b * Ln + i] = rsqrtf(var + 1e-5f);
  }
}

// ---------------- fused normalize + out projection (sorted domain), register-blocked
__global__ __launch_bounds__(256) void k_outproj(const float* __restrict__ ys,
    const float* __restrict__ mu_v, const float* __restrict__ rs_v,
    const float* __restrict__ ln_g, const float* __restrict__ ln_b,
    const float* __restrict__ out_wT, const float* __restrict__ out_b,
    float* __restrict__ outs) {
  int gid = blockIdx.x;
  int g = gid % 3;
  int lt = (gid / 3) % 16;
  int b = gid / 48;
  int i = lt * 256 + threadIdx.x;
  int c0 = g * 64;
  const float* yp = ys + (size_t)b * Dn * Ln + i;
  float mu = mu_v[b * Ln + i], rs = rs_v[b * Ln + i];
  float acc[64];
#pragma unroll
  for (int j = 0; j < 64; ++j) acc[j] = out_b[c0 + j];
  for (int d = 0; d < Dn; d += 2) {
    float y0 = yp[(size_t)d * Ln];
    float y1 = yp[(size_t)(d + 1) * Ln];
    float v0 = (y0 - mu) * rs * ln_g[d] + ln_b[d];
    float v1 = (y1 - mu) * rs * ln_g[d + 1] + ln_b[d + 1];
    const float* w0 = out_wT + d * Cn + c0;
    const float* w1 = out_wT + (d + 1) * Cn + c0;
#pragma unroll
    for (int j = 0; j < 64; ++j) acc[j] += w0[j] * v0 + w1[j] * v1;
  }
  float* op = outs + ((size_t)b * Ln + i) * Cn + c0;
#pragma unroll
  for (int j = 0; j < 64; ++j) op[j] = acc[j];
}

// ---------------- inverse-permute + transpose to (B, C, L)
__global__ __launch_bounds__(256) void k_perm(const float* __restrict__ outs,
    const int* __restrict__ iidx, float* __restrict__ out) {
  int b = blockIdx.x >> 6;
  int lt = blockIdx.x & 63;
  int l0 = lt * 64;
  __shared__ float ot[64][Cn + 1];
  __shared__ int ivs[64];
  if (threadIdx.x < 64) ivs[threadIdx.x] = iidx[(size_t)b * Ln + l0 + threadIdx.x];
  __syncthreads();
  for (int e = threadIdx.x; e < 3072; e += 256) {
    int ii = e / 48;
    int qq = (e % 48) * 4;
    const float* sp = outs + ((size_t)b * Ln + ivs[ii]) * Cn + qq;
    float4 vv = *(const float4*)sp;
    ot[ii][qq] = vv.x;
    ot[ii][qq + 1] = vv.y;
    ot[ii][qq + 2] = vv.z;
    ot[ii][qq + 3] = vv.w;
  }
  __syncthreads();
  for (int e = threadIdx.x; e < 64 * Cn; e += 256) {
    int c = e >> 6;
    int ii = e & 63;
    out[((size_t)b * Cn + c) * Ln + l0 + ii] = ot[ii][c];
  }
}

extern "C" void kernel_launch(void* const* d_in, const int* in_sizes, int n_in,
                              void* d_out, int out_size, void* d_ws, size_t ws_size,
                              hipStream_t stream) {
  (void)in_sizes; (void)n_in; (void)out_size; (void)ws_size;
  const float* x = (const float*)d_in[0];
  const float* gumbel = (const float*)d_in[1];
  const float* emb_B = (const float*)d_in[2];
  const float* emb_A = (const float*)d_in[3];
  const float* route_w1 = (const float*)d_in[4];
  const float* route_b1 = (const float*)d_in[5];
  const float* route_w2 = (const float*)d_in[6];
  const float* route_b2 = (const float*)d_in[7];
  const float* in_proj_w = (const float*)d_in[8];
  const float* in_proj_b = (const float*)d_in[9];
  const float* cpe_w = (const float*)d_in[10];
  const float* cpe_b = (const float*)d_in[11];
  const float* x_proj_w = (const float*)d_in[12];
  const float* dt_w = (const float*)d_in[13];
  const float* dt_b = (const float*)d_in[14];
  const float* A_logs = (const float*)d_in[15];
  const float* Ds = (const float*)d_in[16];
  const float* ln_g = (const float*)d_in[17];
  const float* ln_b = (const float*)d_in[18];
  const float* out_w = (const float*)d_in[19];
  const float* out_b = (const float*)d_in[20];

  float* ws = (float*)d_ws;
  float* v0 = ws;                     // 12582912 (later ys, (B,D,L))
  float* v = v0 + 12582912;           // 12582912 (later out_sorted)
  float* u = v + 12582912;            // 12582912
  float* dl = u + 12582912;           // 12582912
  float* xd = dl + 12582912;          // 1835008
  float* ap = xd + 1835008;           // 786432
  float* hc = ap + 786432;            // 786432
  float* hs = hc + 786432;            // 786432
  float* fe = hs + 786432;            // 1024
  float* owT = fe + 1024;             // 73728
  float* xpT = owT + 73728;           // 21504
  int* idxp = (int*)(xpT + 21504);    // 32768
  int* sidx = idxp + 32768;           // 32768
  int* iidx = sidx + 32768;           // 32768
  float* muv = (float*)(iidx + 32768);// 32768
  float* rsv = muv + 32768;           // 32768

  k_prep<<<288, 256, 0, stream>>>(emb_B, emb_A, x_proj_w, out_w, fe, xpT, owT);
  k_route<<<128, 256, 0, stream>>>(x, gumbel, route_w1, route_b1, route_w2, route_b2, idxp);
  k_sort<<<8, 64, 0, stream>>>(idxp, sidx, iidx);
  k_inproj<<<768, 256, 0, stream>>>(x, in_proj_w, in_proj_b, v0);
  k_cpe<<<Bn * Dn, 256, 0, stream>>>(v0, cpe_w, cpe_b, v);
  k_gather<<<512, 256, 0, stream>>>(v, sidx, u);
  k_xdbl<<<256, 256, 0, stream>>>(u, xpT, fe, idxp, xd);
  k_delta<<<768, 256, 0, stream>>>(xd, dt_w, dt_b, dl);
  k_scan1<<<3072, 256, 0, stream>>>(dl, u, xd, A_logs, ap, hc);
  k_scan2<<<192, 256, 0, stream>>>(ap, hc, hs);
  k_scan3<<<3072, 256, 0, stream>>>(dl, u, xd, A_logs, Ds, hs, v0);
  k_ln<<<256, 256, 0, stream>>>(v0, muv, rsv);
  k_outproj<<<384, 256, 0, stream>>>(v0, muv, rsv, ln_g, ln_b, owT, out_b, v);
  k_perm<<<512, 256, 0, stream>>>(v, iidx, (float*)d_out);
}

// Round 3
// 1252.343 us; speedup vs baseline: 1.1448x; 1.0203x over previous
//
#include <hip/hip_runtime.h>

#define Bn 8
#define Cn 192
#define CRn 64
#define Dn 384
#define Ln 4096
#define Hn 64
#define Wn 64
#define NTOKn 64
#define NSTn 16
#define Rn 24
#define IRn 128
#define CHn 16
#define LCn 256

// ---------------- prep: full_emb = emb_B@emb_A, transpose x_proj_w and out_w
__global__ __launch_bounds__(256) void k_prep(const float* __restrict__ emb_B,
    const float* __restrict__ emb_A, const float* __restrict__ x_proj_w,
    const float* __restrict__ out_w, float* __restrict__ full_emb,
    float* __restrict__ xprojT, float* __restrict__ out_wT) {
  int t = blockIdx.x * 256 + threadIdx.x;
  if (t < NTOKn * NSTn) {
    int tok = t / NSTn, s = t % NSTn;
    float acc = 0.f;
    for (int k = 0; k < IRn; ++k) acc += emb_B[tok * IRn + k] * emb_A[k * NSTn + s];
    full_emb[t] = acc;
  }
  if (t < Dn * 56) {
    int d = t / 56, j = t % 56;
    xprojT[t] = x_proj_w[j * Dn + d];
  }
  if (t < Dn * Cn) {
    int d = t / Cn, c = t % Cn;
    out_wT[t] = out_w[c * Dn + d];
  }
}

// ---------------- routing: idx = argmax over 64 classes of (W2 gelu(W1 x + b1) + b2 + gumbel)
__global__ __launch_bounds__(256) void k_route(const float* __restrict__ x,
    const float* __restrict__ gumbel, const float* __restrict__ w1,
    const float* __restrict__ b1, const float* __restrict__ w2,
    const float* __restrict__ b2, int* __restrict__ idx_out) {
  int b = blockIdx.x >> 4;
  int l = ((blockIdx.x & 15) << 8) + threadIdx.x;
  const float* xb = x + (size_t)b * Cn * Ln + l;
  float h1[CRn];
#pragma unroll
  for (int j = 0; j < CRn; ++j) h1[j] = b1[j];
  for (int c = 0; c < Cn; c += 4) {
    float x0 = xb[(size_t)c * Ln];
    float x1 = xb[(size_t)(c + 1) * Ln];
    float x2 = xb[(size_t)(c + 2) * Ln];
    float x3 = xb[(size_t)(c + 3) * Ln];
#pragma unroll
    for (int j = 0; j < CRn; ++j) {
      const float* wr = w1 + j * Cn + c;
      h1[j] += wr[0] * x0 + wr[1] * x1 + wr[2] * x2 + wr[3] * x3;
    }
  }
#pragma unroll
  for (int j = 0; j < CRn; ++j) {
    float v = h1[j];
    h1[j] = 0.5f * v * (1.f + erff(v * 0.70710678118654752f));  // exact gelu
  }
  const float* gp = gumbel + ((size_t)b * Ln + l) * NTOKn;
  float best = -3.4e38f;
  int bi = 0;
  for (int k = 0; k < NTOKn; ++k) {
    float s = b2[k];
    const float* wr = w2 + k * CRn;
#pragma unroll
    for (int j = 0; j < CRn; ++j) s += wr[j] * h1[j];
    s += gp[k];
    if (s > best) { best = s; bi = k; }  // first-max wins == jnp.argmax
  }
  idx_out[(size_t)b * Ln + l] = bi;
}

// ---------------- stable counting sort (per batch): sort_idx, inv_idx
__global__ __launch_bounds__(64) void k_sort(const int* __restrict__ idx_in,
    int* __restrict__ sidx, int* __restrict__ iidx) {
  __shared__ int idx_l[Ln];
  __shared__ int hist[NTOKn][NTOKn + 1];  // [class][chunk]
  __shared__ int offs[NTOKn][NTOKn + 1];
  __shared__ int sort_l[Ln];
  __shared__ int inv_l[Ln];
  int b = blockIdx.x;
  int lane = threadIdx.x;
  const int* ip = idx_in + (size_t)b * Ln;
  for (int t = lane; t < Ln; t += 64) idx_l[t] = ip[t];
  for (int t = lane; t < NTOKn * (NTOKn + 1); t += 64) (&hist[0][0])[t] = 0;
  __syncthreads();
  {  // phase A: lane = chunk
    int base = lane * 64;
    for (int t = 0; t < 64; ++t) {
      int c = idx_l[base + t];
      hist[c][lane]++;
    }
  }
  __syncthreads();
  {  // phase B: lane = class; exclusive prefix across classes then across chunks
    int tot = 0;
    for (int k = 0; k < 64; ++k) tot += hist[lane][k];
    int incl = tot;
    for (int o = 1; o < 64; o <<= 1) {
      int v = __shfl_up(incl, o, 64);
      if (lane >= o) incl += v;
    }
    int run = incl - tot;
    for (int k = 0; k < 64; ++k) { offs[lane][k] = run; run += hist[lane][k]; }
  }
  __syncthreads();
  {  // phase C: lane = chunk, stable within chunk
    int base = lane * 64;
    for (int t = 0; t < 64; ++t) {
      int gl = base + t;
      int c = idx_l[gl];
      int p = offs[c][lane]++;
      sort_l[p] = gl;
      inv_l[gl] = p;
    }
  }
  __syncthreads();
  for (int t = lane; t < Ln; t += 64) {
    sidx[(size_t)b * Ln + t] = sort_l[t];
    iidx[(size_t)b * Ln + t] = inv_l[t];
  }
}

// ---------------- in_proj: v0[b,d,l] = sum_c W[d,c] x[b,c,l] + bias[d]
__global__ __launch_bounds__(256) void k_inproj(const float* __restrict__ x,
    const float* __restrict__ w, const float* __restrict__ bias,
    float* __restrict__ v0) {
  int gid = blockIdx.x;
  int g = gid % 6;
  int lt = (gid / 6) % 16;
  int b = gid / 96;
  int l = lt * 256 + threadIdx.x;
  int d0 = g * 64;
  const float* xb = x + (size_t)b * Cn * Ln + l;
  float acc[64];
#pragma unroll
  for (int dd = 0; dd < 64; ++dd) acc[dd] = bias[d0 + dd];
  for (int c = 0; c < Cn; c += 8) {
    float xv[8];
#pragma unroll
    for (int k = 0; k < 8; ++k) xv[k] = xb[(size_t)(c + k) * Ln];
#pragma unroll
    for (int dd = 0; dd < 64; ++dd) {
      const float* wr = w + (d0 + dd) * Cn + c;
#pragma unroll
      for (int k = 0; k < 8; ++k) acc[dd] += wr[k] * xv[k];
    }
  }
  float* vp = v0 + ((size_t)b * Dn + d0) * Ln + l;
#pragma unroll
  for (int dd = 0; dd < 64; ++dd) vp[(size_t)dd * Ln] = acc[dd];
}

// ---------------- depthwise 3x3 SAME conv + sigmoid gate
__global__ __launch_bounds__(256) void k_cpe(const float* __restrict__ v0,
    const float* __restrict__ cw, const float* __restrict__ cb,
    float* __restrict__ v) {
  int b = blockIdx.x / Dn;
  int d = blockIdx.x % Dn;
  __shared__ float plane[Hn][Wn + 1];
  const float* src = v0 + ((size_t)b * Dn + d) * Ln;
  float* dst = v + ((size_t)b * Dn + d) * Ln;
  for (int i = threadIdx.x; i < Ln; i += 256) plane[i >> 6][i & 63] = src[i];
  float kw[9];
#pragma unroll
  for (int k = 0; k < 9; ++k) kw[k] = cw[d * 9 + k];
  float bb = cb[d];
  __syncthreads();
  for (int i = threadIdx.x; i < Ln; i += 256) {
    int y = i >> 6, xx = i & 63;
    float s = bb;
#pragma unroll
    for (int ky = 0; ky < 3; ++ky) {
      int yy = y + ky - 1;
      if (yy < 0 || yy >= Hn) continue;
#pragma unroll
      for (int kx = 0; kx < 3; ++kx) {
        int x2 = xx + kx - 1;
        if (x2 < 0 || x2 >= Wn) continue;
        s += plane[yy][x2] * kw[ky * 3 + kx];
      }
    }
    float g = 1.f / (1.f + expf(-s));
    dst[i] = plane[y][xx] * g;
  }
}

// ---------------- gather u[b,d,i] = v[b,d,sidx[b,i]]
__global__ __launch_bounds__(256) void k_gather(const float* __restrict__ v,
    const int* __restrict__ sidx, float* __restrict__ u) {
  int b = blockIdx.x >> 6;
  int it = blockIdx.x & 63;
  int i = it * 64 + (threadIdx.x & 63);
  int q = threadIdx.x >> 6;
  int sj = sidx[(size_t)b * Ln + i];
  const float* vb = v + (size_t)b * Dn * Ln;
  float* ub = u + (size_t)b * Dn * Ln;
  for (int dc = 0; dc < Dn / 4; ++dc) {
    int d = dc * 4 + q;
    ub[(size_t)d * Ln + i] = vb[(size_t)d * Ln + sj];
  }
}

// ---------------- x_dbl[b,j,i] = sum_d x_proj_w[j,d] u[b,d,i]  (+ full_emb[idx] on Cs rows)
__global__ __launch_bounds__(256) void k_xdbl(const float* __restrict__ u,
    const float* __restrict__ xprojT, const float* __restrict__ femb,
    const int* __restrict__ idx_in, float* __restrict__ xdbl) {
  int gid = blockIdx.x;
  int jg = gid & 3;
  int lt = (gid >> 2) & 15;
  int b = gid >> 6;
  int i = lt * 256 + threadIdx.x;
  int j0 = jg * 14;
  const float* ub = u + (size_t)b * Dn * Ln + i;
  float acc[14];
#pragma unroll
  for (int jj = 0; jj < 14; ++jj) acc[jj] = 0.f;
  for (int d = 0; d < Dn; d += 4) {
    float uv[4];
#pragma unroll
    for (int k = 0; k < 4; ++k) uv[k] = ub[(size_t)(d + k) * Ln];
#pragma unroll
    for (int k = 0; k < 4; ++k) {
      const float* wr = xprojT + (d + k) * 56 + j0;
#pragma unroll
      for (int jj = 0; jj < 14; ++jj) acc[jj] += wr[jj] * uv[k];
    }
  }
  int cls = idx_in[(size_t)b * Ln + i];  // ORIGINAL-order idx (reference adds prompt unsorted)
  float* op = xdbl + ((size_t)b * 56 + j0) * Ln + i;
#pragma unroll
  for (int jj = 0; jj < 14; ++jj) {
    int j = j0 + jj;
    float val = acc[jj];
    if (j >= 40) val += femb[cls * NSTn + (j - 40)];
    op[(size_t)jj * Ln] = val;
  }
}

// ---------------- delta = softplus(dt_w @ dts + dt_b)
__global__ __launch_bounds__(256) void k_delta(const float* __restrict__ xdbl,
    const float* __restrict__ dt_w, const float* __restrict__ dt_b,
    float* __restrict__ delta) {
  int gid = blockIdx.x;
  int g = gid % 6;
  int lt = (gid / 6) % 16;
  int b = gid / 96;
  int i = lt * 256 + threadIdx.x;
  int d0 = g * 64;
  const float* tp = xdbl + (size_t)b * 56 * Ln + i;
  float acc[64];
#pragma unroll
  for (int dd = 0; dd < 64; ++dd) acc[dd] = dt_b[d0 + dd];
  for (int r = 0; r < Rn; ++r) {
    float tv = tp[(size_t)r * Ln];
#pragma unroll
    for (int dd = 0; dd < 64; ++dd) acc[dd] += dt_w[(d0 + dd) * Rn + r] * tv;
  }
  float* op = delta + ((size_t)b * Dn + d0) * Ln + i;
#pragma unroll
  for (int dd = 0; dd < 64; ++dd) {
    float s = acc[dd];
    op[(size_t)dd * Ln] = fmaxf(s, 0.f) + log1pf(expf(-fabsf(s)));
  }
}

// ---------------- scan phase 1: per-chunk (prod a, h-from-zero)
__global__ __launch_bounds__(256) void k_scan1(const float* __restrict__ delta,
    const float* __restrict__ u, const float* __restrict__ xdbl,
    const float* __restrict__ A_logs, float* __restrict__ aprod_o,
    float* __restrict__ hacc_o) {
  int gid = blockIdx.x;
  int dg = gid % 24;
  int ck = (gid / 24) % CHn;
  int b = gid / 384;
  int tid = threadIdx.x;
  int n = tid & 15;
  int d = dg * 16 + (tid >> 4);
  float Av = -expf(A_logs[d * NSTn + n]);
  const float* dp = delta + ((size_t)b * Dn + d) * Ln + ck * LCn;
  const float* up = u + ((size_t)b * Dn + d) * Ln + ck * LCn;
  const float* bp = xdbl + ((size_t)b * 56 + 24 + n) * Ln + ck * LCn;
  float ap = 1.f, hc = 0.f;
  for (int t = 0; t < LCn; t += 4) {
    float4 d4 = *(const float4*)(dp + t);
    float4 u4 = *(const float4*)(up + t);
    float4 b4 = *(const float4*)(bp + t);
    float dv[4] = {d4.x, d4.y, d4.z, d4.w};
    float uv[4] = {u4.x, u4.y, u4.z, u4.w};
    float bv[4] = {b4.x, b4.y, b4.z, b4.w};
#pragma unroll
    for (int q = 0; q < 4; ++q) {
      float a = __expf(dv[q] * Av);
      hc = hc * a + dv[q] * uv[q] * bv[q];
      ap *= a;
    }
  }
  size_t o = ((size_t)(b * CHn + ck) * Dn + dg * 16) * NSTn + tid;
  aprod_o[o] = ap;
  hacc_o[o] = hc;
}

// ---------------- scan phase 2: combine chunks sequentially (16 steps)
__global__ __launch_bounds__(256) void k_scan2(const float* __restrict__ aprod,
    const float* __restrict__ hacc, float* __restrict__ hstart) {
  int gid = blockIdx.x * 256 + threadIdx.x;  // over B*D*NST
  int b = gid / (Dn * NSTn);
  int dn = gid % (Dn * NSTn);
  float h = 0.f;
  for (int k = 0; k < CHn; ++k) {
    size_t o = (size_t)(b * CHn + k) * Dn * NSTn + dn;
    hstart[o] = h;
    h = h * aprod[o] + hacc[o];
  }
}

// ---------------- scan phase 3: replay with h_start, emit y (+Ds*u) in (B,D,L) layout
__global__ __launch_bounds__(256) void k_scan3(const float* __restrict__ delta,
    const float* __restrict__ u, const float* __restrict__ xdbl,
    const float* __restrict__ A_logs, const float* __restrict__ Ds,
    const float* __restrict__ hstart, float* __restrict__ ys) {
  int gid = blockIdx.x;
  int dg = gid % 24;
  int ck = (gid / 24) % CHn;
  int b = gid / 384;
  int tid = threadIdx.x;
  int n = tid & 15;
  int dloc = tid >> 4;
  int d = dg * 16 + dloc;
  float Av = -expf(A_logs[d * NSTn + n]);
  float Dv = Ds[d];
  const float* dp = delta + ((size_t)b * Dn + d) * Ln + ck * LCn;
  const float* up = u + ((size_t)b * Dn + d) * Ln + ck * LCn;
  const float* bp = xdbl + ((size_t)b * 56 + 24 + n) * Ln + ck * LCn;
  const float* cp = xdbl + ((size_t)b * 56 + 40 + n) * Ln + ck * LCn;
  float h = hstart[((size_t)(b * CHn + ck) * Dn + dg * 16) * NSTn + tid];
  __shared__ float ylds[16][65];
  for (int t64 = 0; t64 < LCn / 64; ++t64) {
    for (int t = 0; t < 64; t += 4) {
      int tt = t64 * 64 + t;
      float4 d4 = *(const float4*)(dp + tt);
      float4 u4 = *(const float4*)(up + tt);
      float4 b4 = *(const float4*)(bp + tt);
      float4 c4 = *(const float4*)(cp + tt);
      float dv[4] = {d4.x, d4.y, d4.z, d4.w};
      float uv[4] = {u4.x, u4.y, u4.z, u4.w};
      float bv[4] = {b4.x, b4.y, b4.z, b4.w};
      float cv[4] = {c4.x, c4.y, c4.z, c4.w};
#pragma unroll
      for (int q = 0; q < 4; ++q) {
        float a = __expf(dv[q] * Av);
        h = h * a + dv[q] * uv[q] * bv[q];
        float p = h * cv[q];
        p += __shfl_xor(p, 8, 16);
        p += __shfl_xor(p, 4, 16);
        p += __shfl_xor(p, 2, 16);
        p += __shfl_xor(p, 1, 16);
        if (n == 0) ylds[dloc][t + q] = p + Dv * uv[q];
      }
    }
    __syncthreads();
    int i0 = ck * LCn + t64 * 64;
    for (int e = tid; e < 16 * 64; e += 256) {
      int dd = e >> 6, tt = e & 63;
      ys[((size_t)b * Dn + dg * 16 + dd) * Ln + i0 + tt] = ylds[dd][tt];
    }
    __syncthreads();
  }
}

// ---------------- LN stats per sorted token: mu, rsigma  (ys in (B,D,L))
__global__ __launch_bounds__(256) void k_ln(const float* __restrict__ ys,
    float* __restrict__ mu_o, float* __restrict__ rs_o) {
  int b = blockIdx.x >> 6;
  int i0 = (blockIdx.x & 63) << 6;
  int t = threadIdx.x & 63;
  int q = threadIdx.x >> 6;
  int i = i0 + t;
  const float* p = ys + ((size_t)b * Dn + q * 96) * Ln + i;
  float s = 0.f, sq = 0.f;
  for (int d = 0; d < 96; d += 2) {
    float v0 = p[(size_t)d * Ln];
    float v1 = p[(size_t)(d + 1) * Ln];
    s += v0 + v1;
    sq += v0 * v0 + v1 * v1;
  }
  __shared__ float sh_s[4][64], sh_q[4][64];
  sh_s[q][t] = s;
  sh_q[q][t] = sq;
  __syncthreads();
  if (q == 0) {
    float ts = s + sh_s[1][t] + sh_s[2][t] + sh_s[3][t];
    float tq = sq + sh_q[1][t] + sh_q[2][t] + sh_q[3][t];
    float mu = ts * (1.f / Dn);
    float var = tq * (1.f / Dn) - mu * mu;
    mu_o[b * Ln + i] = mu;
    rs_o[b * Ln + i] = rsqrtf(var + 1e-5f);
  }
}

// ---------------- fused normalize + out projection (sorted domain), register-blocked
__global__ __launch_bounds__(256) void k_outproj(const float* __restrict__ ys,
    const float* __restrict__ mu_v, const float* __restrict__ rs_v,
    const float* __restrict__ ln_g, const float* __restrict__ ln_b,
    const float* __restrict__ out_wT, const float* __restrict__ out_b,
    float* __restrict__ outs) {
  int gid = blockIdx.x;
  int g = gid % 6;
  int lt = (gid / 6) % 16;
  int b = gid / 96;
  int i = lt * 256 + threadIdx.x;
  int c0 = g * 32;
  const float* yp = ys + (size_t)b * Dn * Ln + i;
  float mu = mu_v[b * Ln + i], rs = rs_v[b * Ln + i];
  float acc[32];
#pragma unroll
  for (int j = 0; j < 32; ++j) acc[j] = out_b[c0 + j];
  for (int d = 0; d < Dn; d += 4) {
    float yv[4];
#pragma unroll
    for (int k = 0; k < 4; ++k) yv[k] = yp[(size_t)(d + k) * Ln];
#pragma unroll
    for (int k = 0; k < 4; ++k) {
      float v = (yv[k] - mu) * rs * ln_g[d + k] + ln_b[d + k];
      const float* wr = out_wT + (d + k) * Cn + c0;
#pragma unroll
      for (int j = 0; j < 32; ++j) acc[j] += wr[j] * v;
    }
  }
  float* op = outs + ((size_t)b * Ln + i) * Cn + c0;
#pragma unroll
  for (int j = 0; j < 32; ++j) op[j] = acc[j];
}

// ---------------- inverse-permute + transpose to (B, C, L)
__global__ __launch_bounds__(256) void k_perm(const float* __restrict__ outs,
    const int* __restrict__ iidx, float* __restrict__ out) {
  int b = blockIdx.x >> 6;
  int lt = blockIdx.x & 63;
  int l0 = lt * 64;
  __shared__ float ot[64][Cn + 1];
  __shared__ int ivs[64];
  if (threadIdx.x < 64) ivs[threadIdx.x] = iidx[(size_t)b * Ln + l0 + threadIdx.x];
  __syncthreads();
  for (int e = threadIdx.x; e < 3072; e += 256) {
    int ii = e / 48;
    int qq = (e % 48) * 4;
    const float* sp = outs + ((size_t)b * Ln + ivs[ii]) * Cn + qq;
    float4 vv = *(const float4*)sp;
    ot[ii][qq] = vv.x;
    ot[ii][qq + 1] = vv.y;
    ot[ii][qq + 2] = vv.z;
    ot[ii][qq + 3] = vv.w;
  }
  __syncthreads();
  for (int e = threadIdx.x; e < 64 * Cn; e += 256) {
    int c = e >> 6;
    int ii = e & 63;
    out[((size_t)b * Cn + c) * Ln + l0 + ii] = ot[ii][c];
  }
}

extern "C" void kernel_launch(void* const* d_in, const int* in_sizes, int n_in,
                              void* d_out, int out_size, void* d_ws, size_t ws_size,
                              hipStream_t stream) {
  (void)in_sizes; (void)n_in; (void)out_size; (void)ws_size;
  const float* x = (const float*)d_in[0];
  const float* gumbel = (const float*)d_in[1];
  const float* emb_B = (const float*)d_in[2];
  const float* emb_A = (const float*)d_in[3];
  const float* route_w1 = (const float*)d_in[4];
  const float* route_b1 = (const float*)d_in[5];
  const float* route_w2 = (const float*)d_in[6];
  const float* route_b2 = (const float*)d_in[7];
  const float* in_proj_w = (const float*)d_in[8];
  const float* in_proj_b = (const float*)d_in[9];
  const float* cpe_w = (const float*)d_in[10];
  const float* cpe_b = (const float*)d_in[11];
  const float* x_proj_w = (const float*)d_in[12];
  const float* dt_w = (const float*)d_in[13];
  const float* dt_b = (const float*)d_in[14];
  const float* A_logs = (const float*)d_in[15];
  const float* Ds = (const float*)d_in[16];
  const float* ln_g = (const float*)d_in[17];
  const float* ln_b = (const float*)d_in[18];
  const float* out_w = (const float*)d_in[19];
  const float* out_b = (const float*)d_in[20];

  float* ws = (float*)d_ws;
  float* v0 = ws;                     // 12582912 (later ys, (B,D,L))
  float* v = v0 + 12582912;           // 12582912 (later out_sorted)
  float* u = v + 12582912;            // 12582912
  float* dl = u + 12582912;           // 12582912
  float* xd = dl + 12582912;          // 1835008
  float* ap = xd + 1835008;           // 786432
  float* hc = ap + 786432;            // 786432
  float* hs = hc + 786432;            // 786432
  float* fe = hs + 786432;            // 1024
  float* owT = fe + 1024;             // 73728
  float* xpT = owT + 73728;           // 21504
  int* idxp = (int*)(xpT + 21504);    // 32768
  int* sidx = idxp + 32768;           // 32768
  int* iidx = sidx + 32768;           // 32768
  float* muv = (float*)(iidx + 32768);// 32768
  float* rsv = muv + 32768;           // 32768

  k_prep<<<288, 256, 0, stream>>>(emb_B, emb_A, x_proj_w, out_w, fe, xpT, owT);
  k_route<<<128, 256, 0, stream>>>(x, gumbel, route_w1, route_b1, route_w2, route_b2, idxp);
  k_sort<<<8, 64, 0, stream>>>(idxp, sidx, iidx);
  k_inproj<<<768, 256, 0, stream>>>(x, in_proj_w, in_proj_b, v0);
  k_cpe<<<Bn * Dn, 256, 0, stream>>>(v0, cpe_w, cpe_b, v);
  k_gather<<<512, 256, 0, stream>>>(v, sidx, u);
  k_xdbl<<<512, 256, 0, stream>>>(u, xpT, fe, idxp, xd);
  k_delta<<<768, 256, 0, stream>>>(xd, dt_w, dt_b, dl);
  k_scan1<<<3072, 256, 0, stream>>>(dl, u, xd, A_logs, ap, hc);
  k_scan2<<<192, 256, 0, stream>>>(ap, hc, hs);
  k_scan3<<<3072, 256, 0, stream>>>(dl, u, xd, A_logs, Ds, hs, v0);
  k_ln<<<512, 256, 0, stream>>>(v0, muv, rsv);
  k_outproj<<<768, 256, 0, stream>>>(v0, muv, rsv, ln_g, ln_b, owT, out_b, v);
  k_perm<<<512, 256, 0, stream>>>(v, iidx, (float*)d_out);
}

// Round 4
// 1139.935 us; speedup vs baseline: 1.2577x; 1.0986x over previous
//
#include <hip/hip_runtime.h>

#define Bn 8
#define Cn 192
#define CRn 64
#define Dn 384
#define Ln 4096
#define Hn 64
#define Wn 64
#define NTOKn 64
#define NSTn 16
#define Rn 24
#define IRn 128
#define CHn 16
#define LCn 256

// ---------------- prep: full_emb = emb_B@emb_A, transpose x_proj_w and out_w
__global__ __launch_bounds__(256) void k_prep(const float* __restrict__ emb_B,
    const float* __restrict__ emb_A, const float* __restrict__ x_proj_w,
    const float* __restrict__ out_w, float* __restrict__ full_emb,
    float* __restrict__ xprojT, float* __restrict__ out_wT) {
  int t = blockIdx.x * 256 + threadIdx.x;
  if (t < NTOKn * NSTn) {
    int tok = t / NSTn, s = t % NSTn;
    float acc = 0.f;
    for (int k = 0; k < IRn; ++k) acc += emb_B[tok * IRn + k] * emb_A[k * NSTn + s];
    full_emb[t] = acc;
  }
  if (t < Dn * 56) {
    int d = t / 56, j = t % 56;
    xprojT[t] = x_proj_w[j * Dn + d];
  }
  if (t < Dn * Cn) {
    int d = t / Cn, c = t % Cn;
    out_wT[t] = out_w[c * Dn + d];
  }
}

// ---------------- routing: idx = argmax over 64 classes of (W2 gelu(W1 x + b1) + b2 + gumbel)
__global__ __launch_bounds__(256) void k_route(const float* __restrict__ x,
    const float* __restrict__ gumbel, const float* __restrict__ w1,
    const float* __restrict__ b1, const float* __restrict__ w2,
    const float* __restrict__ b2, int* __restrict__ idx_out) {
  int b = blockIdx.x >> 4;
  int l = ((blockIdx.x & 15) << 8) + threadIdx.x;
  const float* xb = x + (size_t)b * Cn * Ln + l;
  float h1[CRn];
#pragma unroll
  for (int j = 0; j < CRn; ++j) h1[j] = b1[j];
  for (int c = 0; c < Cn; c += 4) {
    float x0 = xb[(size_t)c * Ln];
    float x1 = xb[(size_t)(c + 1) * Ln];
    float x2 = xb[(size_t)(c + 2) * Ln];
    float x3 = xb[(size_t)(c + 3) * Ln];
#pragma unroll
    for (int j = 0; j < CRn; ++j) {
      const float* wr = w1 + j * Cn + c;
      h1[j] += wr[0] * x0 + wr[1] * x1 + wr[2] * x2 + wr[3] * x3;
    }
  }
#pragma unroll
  for (int j = 0; j < CRn; ++j) {
    float v = h1[j];
    h1[j] = 0.5f * v * (1.f + erff(v * 0.70710678118654752f));  // exact gelu
  }
  const float* gp = gumbel + ((size_t)b * Ln + l) * NTOKn;
  float best = -3.4e38f;
  int bi = 0;
  for (int k = 0; k < NTOKn; ++k) {
    float s = b2[k];
    const float* wr = w2 + k * CRn;
#pragma unroll
    for (int j = 0; j < CRn; ++j) s += wr[j] * h1[j];
    s += gp[k];
    if (s > best) { best = s; bi = k; }  // first-max wins == jnp.argmax
  }
  idx_out[(size_t)b * Ln + l] = bi;
}

// ---------------- stable counting sort (per batch): sort_idx, inv_idx
__global__ __launch_bounds__(64) void k_sort(const int* __restrict__ idx_in,
    int* __restrict__ sidx, int* __restrict__ iidx) {
  __shared__ int idx_l[Ln];
  __shared__ int hist[NTOKn][NTOKn + 1];  // [class][chunk]
  __shared__ int offs[NTOKn][NTOKn + 1];
  __shared__ int sort_l[Ln];
  __shared__ int inv_l[Ln];
  int b = blockIdx.x;
  int lane = threadIdx.x;
  const int* ip = idx_in + (size_t)b * Ln;
  for (int t = lane; t < Ln; t += 64) idx_l[t] = ip[t];
  for (int t = lane; t < NTOKn * (NTOKn + 1); t += 64) (&hist[0][0])[t] = 0;
  __syncthreads();
  {  // phase A: lane = chunk
    int base = lane * 64;
    for (int t = 0; t < 64; ++t) {
      int c = idx_l[base + t];
      hist[c][lane]++;
    }
  }
  __syncthreads();
  {  // phase B: lane = class; exclusive prefix across classes then across chunks
    int tot = 0;
    for (int k = 0; k < 64; ++k) tot += hist[lane][k];
    int incl = tot;
    for (int o = 1; o < 64; o <<= 1) {
      int v = __shfl_up(incl, o, 64);
      if (lane >= o) incl += v;
    }
    int run = incl - tot;
    for (int k = 0; k < 64; ++k) { offs[lane][k] = run; run += hist[lane][k]; }
  }
  __syncthreads();
  {  // phase C: lane = chunk, stable within chunk
    int base = lane * 64;
    for (int t = 0; t < 64; ++t) {
      int gl = base + t;
      int c = idx_l[gl];
      int p = offs[c][lane]++;
      sort_l[p] = gl;
      inv_l[gl] = p;
    }
  }
  __syncthreads();
  for (int t = lane; t < Ln; t += 64) {
    sidx[(size_t)b * Ln + t] = sort_l[t];
    iidx[(size_t)b * Ln + t] = inv_l[t];
  }
}

// ---------------- in_proj: v0[b,d,l] = sum_c W[d,c] x[b,c,l] + bias[d]
// d-block = 32 so accumulators provably fit in arch VGPRs (no spill/AGPR traffic)
__global__ __launch_bounds__(256) void k_inproj(const float* __restrict__ x,
    const float* __restrict__ w, const float* __restrict__ bias,
    float* __restrict__ v0) {
  int gid = blockIdx.x;
  int g = gid % 12;
  int lt = (gid / 12) % 16;
  int b = gid / 192;
  int l = lt * 256 + threadIdx.x;
  int d0 = g * 32;
  const float* xb = x + (size_t)b * Cn * Ln + l;
  float acc[32];
#pragma unroll
  for (int dd = 0; dd < 32; ++dd) acc[dd] = bias[d0 + dd];
  for (int c = 0; c < Cn; c += 8) {
    float xv[8];
#pragma unroll
    for (int k = 0; k < 8; ++k) xv[k] = xb[(size_t)(c + k) * Ln];
#pragma unroll
    for (int dd = 0; dd < 32; ++dd) {
      const float* wr = w + (d0 + dd) * Cn + c;
#pragma unroll
      for (int k = 0; k < 8; ++k) acc[dd] += wr[k] * xv[k];
    }
  }
  float* vp = v0 + ((size_t)b * Dn + d0) * Ln + l;
#pragma unroll
  for (int dd = 0; dd < 32; ++dd) vp[(size_t)dd * Ln] = acc[dd];
}

// ---------------- depthwise 3x3 SAME conv + sigmoid gate
__global__ __launch_bounds__(256) void k_cpe(const float* __restrict__ v0,
    const float* __restrict__ cw, const float* __restrict__ cb,
    float* __restrict__ v) {
  int b = blockIdx.x / Dn;
  int d = blockIdx.x % Dn;
  __shared__ float plane[Hn][Wn + 1];
  const float* src = v0 + ((size_t)b * Dn + d) * Ln;
  float* dst = v + ((size_t)b * Dn + d) * Ln;
  for (int i = threadIdx.x; i < Ln; i += 256) plane[i >> 6][i & 63] = src[i];
  float kw[9];
#pragma unroll
  for (int k = 0; k < 9; ++k) kw[k] = cw[d * 9 + k];
  float bb = cb[d];
  __syncthreads();
  for (int i = threadIdx.x; i < Ln; i += 256) {
    int y = i >> 6, xx = i & 63;
    float s = bb;
#pragma unroll
    for (int ky = 0; ky < 3; ++ky) {
      int yy = y + ky - 1;
      if (yy < 0 || yy >= Hn) continue;
#pragma unroll
      for (int kx = 0; kx < 3; ++kx) {
        int x2 = xx + kx - 1;
        if (x2 < 0 || x2 >= Wn) continue;
        s += plane[yy][x2] * kw[ky * 3 + kx];
      }
    }
    float g = 1.f / (1.f + expf(-s));
    dst[i] = plane[y][xx] * g;
  }
}

// ---------------- gather u[b,d,i] = v[b,d,sidx[b,i]]
__global__ __launch_bounds__(256) void k_gather(const float* __restrict__ v,
    const int* __restrict__ sidx, float* __restrict__ u) {
  int b = blockIdx.x >> 6;
  int it = blockIdx.x & 63;
  int i = it * 64 + (threadIdx.x & 63);
  int q = threadIdx.x >> 6;
  int sj = sidx[(size_t)b * Ln + i];
  const float* vb = v + (size_t)b * Dn * Ln;
  float* ub = u + (size_t)b * Dn * Ln;
  for (int dc = 0; dc < Dn / 4; ++dc) {
    int d = dc * 4 + q;
    ub[(size_t)d * Ln + i] = vb[(size_t)d * Ln + sj];
  }
}

// ---------------- x_dbl[b,j,i] = sum_d x_proj_w[j,d] u[b,d,i]  (+ full_emb[idx] on Cs rows)
__global__ __launch_bounds__(256) void k_xdbl(const float* __restrict__ u,
    const float* __restrict__ xprojT, const float* __restrict__ femb,
    const int* __restrict__ idx_in, float* __restrict__ xdbl) {
  int gid = blockIdx.x;
  int jg = gid & 3;
  int lt = (gid >> 2) & 15;
  int b = gid >> 6;
  int i = lt * 256 + threadIdx.x;
  int j0 = jg * 14;
  const float* ub = u + (size_t)b * Dn * Ln + i;
  float acc[14];
#pragma unroll
  for (int jj = 0; jj < 14; ++jj) acc[jj] = 0.f;
  for (int d = 0; d < Dn; d += 4) {
    float uv[4];
#pragma unroll
    for (int k = 0; k < 4; ++k) uv[k] = ub[(size_t)(d + k) * Ln];
#pragma unroll
    for (int k = 0; k < 4; ++k) {
      const float* wr = xprojT + (d + k) * 56 + j0;
#pragma unroll
      for (int jj = 0; jj < 14; ++jj) acc[jj] += wr[jj] * uv[k];
    }
  }
  int cls = idx_in[(size_t)b * Ln + i];  // ORIGINAL-order idx (reference adds prompt unsorted)
  float* op = xdbl + ((size_t)b * 56 + j0) * Ln + i;
#pragma unroll
  for (int jj = 0; jj < 14; ++jj) {
    int j = j0 + jj;
    float val = acc[jj];
    if (j >= 40) val += femb[cls * NSTn + (j - 40)];
    op[(size_t)jj * Ln] = val;
  }
}

// ---------------- delta = softplus(dt_w @ dts + dt_b)  (d-block 32, no spill)
__global__ __launch_bounds__(256) void k_delta(const float* __restrict__ xdbl,
    const float* __restrict__ dt_w, const float* __restrict__ dt_b,
    float* __restrict__ delta) {
  int gid = blockIdx.x;
  int g = gid % 12;
  int lt = (gid / 12) % 16;
  int b = gid / 192;
  int i = lt * 256 + threadIdx.x;
  int d0 = g * 32;
  const float* tp = xdbl + (size_t)b * 56 * Ln + i;
  float acc[32];
#pragma unroll
  for (int dd = 0; dd < 32; ++dd) acc[dd] = dt_b[d0 + dd];
  for (int r = 0; r < Rn; r += 4) {
    float tv[4];
#pragma unroll
    for (int k = 0; k < 4; ++k) tv[k] = tp[(size_t)(r + k) * Ln];
#pragma unroll
    for (int dd = 0; dd < 32; ++dd) {
      const float* wr = dt_w + (d0 + dd) * Rn + r;
#pragma unroll
      for (int k = 0; k < 4; ++k) acc[dd] += wr[k] * tv[k];
    }
  }
  float* op = delta + ((size_t)b * Dn + d0) * Ln + i;
#pragma unroll
  for (int dd = 0; dd < 32; ++dd) {
    float s = acc[dd];
    op[(size_t)dd * Ln] = fmaxf(s, 0.f) + log1pf(expf(-fabsf(s)));
  }
}

// ---------------- scan phase 1: per-chunk (prod a, h-from-zero)
__global__ __launch_bounds__(256) void k_scan1(const float* __restrict__ delta,
    const float* __restrict__ u, const float* __restrict__ xdbl,
    const float* __restrict__ A_logs, float* __restrict__ aprod_o,
    float* __restrict__ hacc_o) {
  int gid = blockIdx.x;
  int dg = gid % 24;
  int ck = (gid / 24) % CHn;
  int b = gid / 384;
  int tid = threadIdx.x;
  int n = tid & 15;
  int d = dg * 16 + (tid >> 4);
  float Av = -expf(A_logs[d * NSTn + n]);
  const float* dp = delta + ((size_t)b * Dn + d) * Ln + ck * LCn;
  const float* up = u + ((size_t)b * Dn + d) * Ln + ck * LCn;
  const float* bp = xdbl + ((size_t)b * 56 + 24 + n) * Ln + ck * LCn;
  float ap = 1.f, hc = 0.f;
  for (int t = 0; t < LCn; t += 4) {
    float4 d4 = *(const float4*)(dp + t);
    float4 u4 = *(const float4*)(up + t);
    float4 b4 = *(const float4*)(bp + t);
    float dv[4] = {d4.x, d4.y, d4.z, d4.w};
    float uv[4] = {u4.x, u4.y, u4.z, u4.w};
    float bv[4] = {b4.x, b4.y, b4.z, b4.w};
#pragma unroll
    for (int q = 0; q < 4; ++q) {
      float a = __expf(dv[q] * Av);
      hc = hc * a + dv[q] * uv[q] * bv[q];
      ap *= a;
    }
  }
  size_t o = ((size_t)(b * CHn + ck) * Dn + dg * 16) * NSTn + tid;
  aprod_o[o] = ap;
  hacc_o[o] = hc;
}

// ---------------- scan phase 2: combine chunks sequentially (16 steps)
__global__ __launch_bounds__(256) void k_scan2(const float* __restrict__ aprod,
    const float* __restrict__ hacc, float* __restrict__ hstart) {
  int gid = blockIdx.x * 256 + threadIdx.x;  // over B*D*NST
  int b = gid / (Dn * NSTn);
  int dn = gid % (Dn * NSTn);
  float h = 0.f;
  for (int k = 0; k < CHn; ++k) {
    size_t o = (size_t)(b * CHn + k) * Dn * NSTn + dn;
    hstart[o] = h;
    h = h * aprod[o] + hacc[o];
  }
}

// ---------------- scan phase 3: replay with h_start, emit y (+Ds*u) in (B,D,L) layout
__global__ __launch_bounds__(256) void k_scan3(const float* __restrict__ delta,
    const float* __restrict__ u, const float* __restrict__ xdbl,
    const float* __restrict__ A_logs, const float* __restrict__ Ds,
    const float* __restrict__ hstart, float* __restrict__ ys) {
  int gid = blockIdx.x;
  int dg = gid % 24;
  int ck = (gid / 24) % CHn;
  int b = gid / 384;
  int tid = threadIdx.x;
  int n = tid & 15;
  int dloc = tid >> 4;
  int d = dg * 16 + dloc;
  float Av = -expf(A_logs[d * NSTn + n]);
  float Dv = Ds[d];
  const float* dp = delta + ((size_t)b * Dn + d) * Ln + ck * LCn;
  const float* up = u + ((size_t)b * Dn + d) * Ln + ck * LCn;
  const float* bp = xdbl + ((size_t)b * 56 + 24 + n) * Ln + ck * LCn;
  const float* cp = xdbl + ((size_t)b * 56 + 40 + n) * Ln + ck * LCn;
  float h = hstart[((size_t)(b * CHn + ck) * Dn + dg * 16) * NSTn + tid];
  __shared__ float ylds[16][65];
  for (int t64 = 0; t64 < LCn / 64; ++t64) {
    for (int t = 0; t < 64; t += 4) {
      int tt = t64 * 64 + t;
      float4 d4 = *(const float4*)(dp + tt);
      float4 u4 = *(const float4*)(up + tt);
      float4 b4 = *(const float4*)(bp + tt);
      float4 c4 = *(const float4*)(cp + tt);
      float dv[4] = {d4.x, d4.y, d4.z, d4.w};
      float uv[4] = {u4.x, u4.y, u4.z, u4.w};
      float bv[4] = {b4.x, b4.y, b4.z, b4.w};
      float cv[4] = {c4.x, c4.y, c4.z, c4.w};
#pragma unroll
      for (int q = 0; q < 4; ++q) {
        float a = __expf(dv[q] * Av);
        h = h * a + dv[q] * uv[q] * bv[q];
        float p = h * cv[q];
        p += __shfl_xor(p, 8, 16);
        p += __shfl_xor(p, 4, 16);
        p += __shfl_xor(p, 2, 16);
        p += __shfl_xor(p, 1, 16);
        if (n == 0) ylds[dloc][t + q] = p + Dv * uv[q];
      }
    }
    __syncthreads();
    int i0 = ck * LCn + t64 * 64;
    for (int e = tid; e < 16 * 64; e += 256) {
      int dd = e >> 6, tt = e & 63;
      ys[((size_t)b * Dn + dg * 16 + dd) * Ln + i0 + tt] = ylds[dd][tt];
    }
    __syncthreads();
  }
}

// ---------------- LN stats per sorted token: mu, rsigma  (ys in (B,D,L))
__global__ __launch_bounds__(256) void k_ln(const float* __restrict__ ys,
    float* __restrict__ mu_o, float* __restrict__ rs_o) {
  int b = blockIdx.x >> 6;
  int i0 = (blockIdx.x & 63) << 6;
  int t = threadIdx.x & 63;
  int q = threadIdx.x >> 6;
  int i = i0 + t;
  const float* p = ys + ((size_t)b * Dn + q * 96) * Ln + i;
  float s = 0.f, sq = 0.f;
  for (int d = 0; d < 96; d += 2) {
    float v0 = p[(size_t)d * Ln];
    float v1 = p[(size_t)(d + 1) * Ln];
    s += v0 + v1;
    sq += v0 * v0 + v1 * v1;
  }
  __shared__ float sh_s[4][64], sh_q[4][64];
  sh_s[q][t] = s;
  sh_q[q][t] = sq;
  __syncthreads();
  if (q == 0) {
    float ts = s + sh_s[1][t] + sh_s[2][t] + sh_s[3][t];
    float tq = sq + sh_q[1][t] + sh_q[2][t] + sh_q[3][t];
    float mu = ts * (1.f / Dn);
    float var = tq * (1.f / Dn) - mu * mu;
    mu_o[b * Ln + i] = mu;
    rs_o[b * Ln + i] = rsqrtf(var + 1e-5f);
  }
}

// ---------------- fused normalize + out projection (sorted domain), register-blocked
__global__ __launch_bounds__(256) void k_outproj(const float* __restrict__ ys,
    const float* __restrict__ mu_v, const float* __restrict__ rs_v,
    const float* __restrict__ ln_g, const float* __restrict__ ln_b,
    const float* __restrict__ out_wT, const float* __restrict__ out_b,
    float* __restrict__ outs) {
  int gid = blockIdx.x;
  int g = gid % 6;
  int lt = (gid / 6) % 16;
  int b = gid / 96;
  int i = lt * 256 + threadIdx.x;
  int c0 = g * 32;
  const float* yp = ys + (size_t)b * Dn * Ln + i;
  float mu = mu_v[b * Ln + i], rs = rs_v[b * Ln + i];
  float acc[32];
#pragma unroll
  for (int j = 0; j < 32; ++j) acc[j] = out_b[c0 + j];
  for (int d = 0; d < Dn; d += 4) {
    float yv[4];
#pragma unroll
    for (int k = 0; k < 4; ++k) yv[k] = yp[(size_t)(d + k) * Ln];
#pragma unroll
    for (int k = 0; k < 4; ++k) {
      float v = (yv[k] - mu) * rs * ln_g[d + k] + ln_b[d + k];
      const float* wr = out_wT + (d + k) * Cn + c0;
#pragma unroll
      for (int j = 0; j < 32; ++j) acc[j] += wr[j] * v;
    }
  }
  float* op = outs + ((size_t)b * Ln + i) * Cn + c0;
#pragma unroll
  for (int j = 0; j < 32; ++j) op[j] = acc[j];
}

// ---------------- inverse-permute + transpose to (B, C, L)
__global__ __launch_bounds__(256) void k_perm(const float* __restrict__ outs,
    const int* __restrict__ iidx, float* __restrict__ out) {
  int b = blockIdx.x >> 6;
  int lt = blockIdx.x & 63;
  int l0 = lt * 64;
  __shared__ float ot[64][Cn + 1];
  __shared__ int ivs[64];
  if (threadIdx.x < 64) ivs[threadIdx.x] = iidx[(size_t)b * Ln + l0 + threadIdx.x];
  __syncthreads();
  for (int e = threadIdx.x; e < 3072; e += 256) {
    int ii = e / 48;
    int qq = (e % 48) * 4;
    const float* sp = outs + ((size_t)b * Ln + ivs[ii]) * Cn + qq;
    float4 vv = *(const float4*)sp;
    ot[ii][qq] = vv.x;
    ot[ii][qq + 1] = vv.y;
    ot[ii][qq + 2] = vv.z;
    ot[ii][qq + 3] = vv.w;
  }
  __syncthreads();
  for (int e = threadIdx.x; e < 64 * Cn; e += 256) {
    int c = e >> 6;
    int ii = e & 63;
    out[((size_t)b * Cn + c) * Ln + l0 + ii] = ot[ii][c];
  }
}

extern "C" void kernel_launch(void* const* d_in, const int* in_sizes, int n_in,
                              void* d_out, int out_size, void* d_ws, size_t ws_size,
                              hipStream_t stream) {
  (void)in_sizes; (void)n_in; (void)out_size; (void)ws_size;
  const float* x = (const float*)d_in[0];
  const float* gumbel = (const float*)d_in[1];
  const float* emb_B = (const float*)d_in[2];
  const float* emb_A = (const float*)d_in[3];
  const float* route_w1 = (const float*)d_in[4];
  const float* route_b1 = (const float*)d_in[5];
  const float* route_w2 = (const float*)d_in[6];
  const float* route_b2 = (const float*)d_in[7];
  const float* in_proj_w = (const float*)d_in[8];
  const float* in_proj_b = (const float*)d_in[9];
  const float* cpe_w = (const float*)d_in[10];
  const float* cpe_b = (const float*)d_in[11];
  const float* x_proj_w = (const float*)d_in[12];
  const float* dt_w = (const float*)d_in[13];
  const float* dt_b = (const float*)d_in[14];
  const float* A_logs = (const float*)d_in[15];
  const float* Ds = (const float*)d_in[16];
  const float* ln_g = (const float*)d_in[17];
  const float* ln_b = (const float*)d_in[18];
  const float* out_w = (const float*)d_in[19];
  const float* out_b = (const float*)d_in[20];

  float* ws = (float*)d_ws;
  float* v0 = ws;                     // 12582912 (later ys, (B,D,L))
  float* v = v0 + 12582912;           // 12582912 (later out_sorted)
  float* u = v + 12582912;            // 12582912
  float* dl = u + 12582912;           // 12582912
  float* xd = dl + 12582912;          // 1835008
  float* ap = xd + 1835008;           // 786432
  float* hc = ap + 786432;            // 786432
  float* hs = hc + 786432;            // 786432
  float* fe = hs + 786432;            // 1024
  float* owT = fe + 1024;             // 73728
  float* xpT = owT + 73728;           // 21504
  int* idxp = (int*)(xpT + 21504);    // 32768
  int* sidx = idxp + 32768;           // 32768
  int* iidx = sidx + 32768;           // 32768
  float* muv = (float*)(iidx + 32768);// 32768
  float* rsv = muv + 32768;           // 32768

  k_prep<<<288, 256, 0, stream>>>(emb_B, emb_A, x_proj_w, out_w, fe, xpT, owT);
  k_route<<<128, 256, 0, stream>>>(x, gumbel, route_w1, route_b1, route_w2, route_b2, idxp);
  k_sort<<<8, 64, 0, stream>>>(idxp, sidx, iidx);
  k_inproj<<<1536, 256, 0, stream>>>(x, in_proj_w, in_proj_b, v0);
  k_cpe<<<Bn * Dn, 256, 0, stream>>>(v0, cpe_w, cpe_b, v);
  k_gather<<<512, 256, 0, stream>>>(v, sidx, u);
  k_xdbl<<<512, 256, 0, stream>>>(u, xpT, fe, idxp, xd);
  k_delta<<<1536, 256, 0, stream>>>(xd, dt_w, dt_b, dl);
  k_scan1<<<3072, 256, 0, stream>>>(dl, u, xd, A_logs, ap, hc);
  k_scan2<<<192, 256, 0, stream>>>(ap, hc, hs);
  k_scan3<<<3072, 256, 0, stream>>>(dl, u, xd, A_logs, Ds, hs, v0);
  k_ln<<<512, 256, 0, stream>>>(v0, muv, rsv);
  k_outproj<<<768, 256, 0, stream>>>(v0, muv, rsv, ln_g, ln_b, owT, out_b, v);
  k_perm<<<512, 256, 0, stream>>>(v, iidx, (float*)d_out);
}

// Round 5
// 1039.180 us; speedup vs baseline: 1.3797x; 1.0970x over previous
//
#include <hip/hip_runtime.h>

#define Bn 8
#define Cn 192
#define CRn 64
#define Dn 384
#define Ln 4096
#define Hn 64
#define Wn 64
#define NTOKn 64
#define NSTn 16
#define Rn 24
#define IRn 128
#define CHn 32
#define LCn 128

// ---------------- prep: full_emb = emb_B@emb_A, transpose x_proj_w and out_w
__global__ __launch_bounds__(256) void k_prep(const float* __restrict__ emb_B,
    const float* __restrict__ emb_A, const float* __restrict__ x_proj_w,
    const float* __restrict__ out_w, float* __restrict__ full_emb,
    float* __restrict__ xprojT, float* __restrict__ out_wT) {
  int t = blockIdx.x * 256 + threadIdx.x;
  if (t < NTOKn * NSTn) {
    int tok = t / NSTn, s = t % NSTn;
    float acc = 0.f;
    for (int k = 0; k < IRn; ++k) acc += emb_B[tok * IRn + k] * emb_A[k * NSTn + s];
    full_emb[t] = acc;
  }
  if (t < Dn * 56) {
    int d = t / 56, j = t % 56;
    xprojT[t] = x_proj_w[j * Dn + d];
  }
  if (t < Dn * Cn) {
    int d = t / Cn, c = t % Cn;
    out_wT[t] = out_w[c * Dn + d];
  }
}

// ---------------- routing: idx = argmax over 64 classes of (W2 gelu(W1 x + b1) + b2 + gumbel)
__global__ __launch_bounds__(256) void k_route(const float* __restrict__ x,
    const float* __restrict__ gumbel, const float* __restrict__ w1,
    const float* __restrict__ b1, const float* __restrict__ w2,
    const float* __restrict__ b2, int* __restrict__ idx_out) {
  int b = blockIdx.x >> 4;
  int l = ((blockIdx.x & 15) << 8) + threadIdx.x;
  const float* xb = x + (size_t)b * Cn * Ln + l;
  float h1[CRn];
#pragma unroll
  for (int j = 0; j < CRn; ++j) h1[j] = b1[j];
  for (int c = 0; c < Cn; c += 4) {
    float x0 = xb[(size_t)c * Ln];
    float x1 = xb[(size_t)(c + 1) * Ln];
    float x2 = xb[(size_t)(c + 2) * Ln];
    float x3 = xb[(size_t)(c + 3) * Ln];
#pragma unroll
    for (int j = 0; j < CRn; ++j) {
      const float* wr = w1 + j * Cn + c;
      h1[j] += wr[0] * x0 + wr[1] * x1 + wr[2] * x2 + wr[3] * x3;
    }
  }
#pragma unroll
  for (int j = 0; j < CRn; ++j) {
    float v = h1[j];
    h1[j] = 0.5f * v * (1.f + erff(v * 0.70710678118654752f));  // exact gelu
  }
  const float* gp = gumbel + ((size_t)b * Ln + l) * NTOKn;
  float best = -3.4e38f;
  int bi = 0;
  for (int k = 0; k < NTOKn; ++k) {
    float s = b2[k];
    const float* wr = w2 + k * CRn;
#pragma unroll
    for (int j = 0; j < CRn; ++j) s += wr[j] * h1[j];
    s += gp[k];
    if (s > best) { best = s; bi = k; }  // first-max wins == jnp.argmax
  }
  idx_out[(size_t)b * Ln + l] = bi;
}

// ---------------- stable counting sort (per batch): sort_idx, inv_idx
__global__ __launch_bounds__(64) void k_sort(const int* __restrict__ idx_in,
    int* __restrict__ sidx, int* __restrict__ iidx) {
  __shared__ int idx_l[Ln];
  __shared__ int hist[NTOKn][NTOKn + 1];  // [class][chunk]
  __shared__ int offs[NTOKn][NTOKn + 1];
  __shared__ int sort_l[Ln];
  __shared__ int inv_l[Ln];
  int b = blockIdx.x;
  int lane = threadIdx.x;
  const int* ip = idx_in + (size_t)b * Ln;
  for (int t = lane; t < Ln; t += 64) idx_l[t] = ip[t];
  for (int t = lane; t < NTOKn * (NTOKn + 1); t += 64) (&hist[0][0])[t] = 0;
  __syncthreads();
  {  // phase A: lane = chunk
    int base = lane * 64;
    for (int t = 0; t < 64; ++t) {
      int c = idx_l[base + t];
      hist[c][lane]++;
    }
  }
  __syncthreads();
  {  // phase B: lane = class; exclusive prefix across classes then across chunks
    int tot = 0;
    for (int k = 0; k < 64; ++k) tot += hist[lane][k];
    int incl = tot;
    for (int o = 1; o < 64; o <<= 1) {
      int v = __shfl_up(incl, o, 64);
      if (lane >= o) incl += v;
    }
    int run = incl - tot;
    for (int k = 0; k < 64; ++k) { offs[lane][k] = run; run += hist[lane][k]; }
  }
  __syncthreads();
  {  // phase C: lane = chunk, stable within chunk
    int base = lane * 64;
    for (int t = 0; t < 64; ++t) {
      int gl = base + t;
      int c = idx_l[gl];
      int p = offs[c][lane]++;
      sort_l[p] = gl;
      inv_l[gl] = p;
    }
  }
  __syncthreads();
  for (int t = lane; t < Ln; t += 64) {
    sidx[(size_t)b * Ln + t] = sort_l[t];
    iidx[(size_t)b * Ln + t] = inv_l[t];
  }
}

// ---------------- in_proj: v0[b,d,l] = sum_c W[d,c] x[b,c,l] + bias[d]
__global__ __launch_bounds__(256) void k_inproj(const float* __restrict__ x,
    const float* __restrict__ w, const float* __restrict__ bias,
    float* __restrict__ v0) {
  int gid = blockIdx.x;
  int g = gid % 12;
  int lt = (gid / 12) % 16;
  int b = gid / 192;
  int l = lt * 256 + threadIdx.x;
  int d0 = g * 32;
  const float* xb = x + (size_t)b * Cn * Ln + l;
  float acc[32];
#pragma unroll
  for (int dd = 0; dd < 32; ++dd) acc[dd] = bias[d0 + dd];
  for (int c = 0; c < Cn; c += 8) {
    float xv[8];
#pragma unroll
    for (int k = 0; k < 8; ++k) xv[k] = xb[(size_t)(c + k) * Ln];
#pragma unroll
    for (int dd = 0; dd < 32; ++dd) {
      const float* wr = w + (d0 + dd) * Cn + c;
#pragma unroll
      for (int k = 0; k < 8; ++k) acc[dd] += wr[k] * xv[k];
    }
  }
  float* vp = v0 + ((size_t)b * Dn + d0) * Ln + l;
#pragma unroll
  for (int dd = 0; dd < 32; ++dd) vp[(size_t)dd * Ln] = acc[dd];
}

// ---------------- depthwise 3x3 SAME conv + sigmoid gate
__global__ __launch_bounds__(256) void k_cpe(const float* __restrict__ v0,
    const float* __restrict__ cw, const float* __restrict__ cb,
    float* __restrict__ v) {
  int b = blockIdx.x / Dn;
  int d = blockIdx.x % Dn;
  __shared__ float plane[Hn][Wn + 1];
  const float* src = v0 + ((size_t)b * Dn + d) * Ln;
  float* dst = v + ((size_t)b * Dn + d) * Ln;
  for (int i = threadIdx.x; i < Ln; i += 256) plane[i >> 6][i & 63] = src[i];
  float kw[9];
#pragma unroll
  for (int k = 0; k < 9; ++k) kw[k] = cw[d * 9 + k];
  float bb = cb[d];
  __syncthreads();
  for (int i = threadIdx.x; i < Ln; i += 256) {
    int y = i >> 6, xx = i & 63;
    float s = bb;
#pragma unroll
    for (int ky = 0; ky < 3; ++ky) {
      int yy = y + ky - 1;
      if (yy < 0 || yy >= Hn) continue;
#pragma unroll
      for (int kx = 0; kx < 3; ++kx) {
        int x2 = xx + kx - 1;
        if (x2 < 0 || x2 >= Wn) continue;
        s += plane[yy][x2] * kw[ky * 3 + kx];
      }
    }
    float g = 1.f / (1.f + expf(-s));
    dst[i] = plane[y][xx] * g;
  }
}

// ---------------- gather u[b,d,i] = v[b,d,sidx[b,i]]
__global__ __launch_bounds__(256) void k_gather(const float* __restrict__ v,
    const int* __restrict__ sidx, float* __restrict__ u) {
  int b = blockIdx.x >> 6;
  int it = blockIdx.x & 63;
  int i = it * 64 + (threadIdx.x & 63);
  int q = threadIdx.x >> 6;
  int sj = sidx[(size_t)b * Ln + i];
  const float* vb = v + (size_t)b * Dn * Ln;
  float* ub = u + (size_t)b * Dn * Ln;
  for (int dc = 0; dc < Dn / 4; ++dc) {
    int d = dc * 4 + q;
    ub[(size_t)d * Ln + i] = vb[(size_t)d * Ln + sj];
  }
}

// ---------------- x_dbl[b,j,i] = sum_d x_proj_w[j,d] u[b,d,i]  (+ full_emb[idx] on Cs rows)
__global__ __launch_bounds__(256) void k_xdbl(const float* __restrict__ u,
    const float* __restrict__ xprojT, const float* __restrict__ femb,
    const int* __restrict__ idx_in, float* __restrict__ xdbl) {
  int gid = blockIdx.x;
  int jg = gid & 3;
  int lt = (gid >> 2) & 15;
  int b = gid >> 6;
  int i = lt * 256 + threadIdx.x;
  int j0 = jg * 14;
  const float* ub = u + (size_t)b * Dn * Ln + i;
  float acc[14];
#pragma unroll
  for (int jj = 0; jj < 14; ++jj) acc[jj] = 0.f;
  for (int d = 0; d < Dn; d += 4) {
    float uv[4];
#pragma unroll
    for (int k = 0; k < 4; ++k) uv[k] = ub[(size_t)(d + k) * Ln];
#pragma unroll
    for (int k = 0; k < 4; ++k) {
      const float* wr = xprojT + (d + k) * 56 + j0;
#pragma unroll
      for (int jj = 0; jj < 14; ++jj) acc[jj] += wr[jj] * uv[k];
    }
  }
  int cls = idx_in[(size_t)b * Ln + i];  // ORIGINAL-order idx (reference adds prompt unsorted)
  float* op = xdbl + ((size_t)b * 56 + j0) * Ln + i;
#pragma unroll
  for (int jj = 0; jj < 14; ++jj) {
    int j = j0 + jj;
    float val = acc[jj];
    if (j >= 40) val += femb[cls * NSTn + (j - 40)];
    op[(size_t)jj * Ln] = val;
  }
}

// ---------------- delta = softplus(dt_w @ dts + dt_b)  (d-block 32, no spill)
__global__ __launch_bounds__(256) void k_delta(const float* __restrict__ xdbl,
    const float* __restrict__ dt_w, const float* __restrict__ dt_b,
    float* __restrict__ delta) {
  int gid = blockIdx.x;
  int g = gid % 12;
  int lt = (gid / 12) % 16;
  int b = gid / 192;
  int i = lt * 256 + threadIdx.x;
  int d0 = g * 32;
  const float* tp = xdbl + (size_t)b * 56 * Ln + i;
  float acc[32];
#pragma unroll
  for (int dd = 0; dd < 32; ++dd) acc[dd] = dt_b[d0 + dd];
  for (int r = 0; r < Rn; r += 4) {
    float tv[4];
#pragma unroll
    for (int k = 0; k < 4; ++k) tv[k] = tp[(size_t)(r + k) * Ln];
#pragma unroll
    for (int dd = 0; dd < 32; ++dd) {
      const float* wr = dt_w + (d0 + dd) * Rn + r;
#pragma unroll
      for (int k = 0; k < 4; ++k) acc[dd] += wr[k] * tv[k];
    }
  }
  float* op = delta + ((size_t)b * Dn + d0) * Ln + i;
#pragma unroll
  for (int dd = 0; dd < 32; ++dd) {
    float s = acc[dd];
    op[(size_t)dd * Ln] = fmaxf(s, 0.f) + log1pf(expf(-fabsf(s)));
  }
}

// ---------------- scan phase 1: per-chunk (prod a, h-from-zero)
__global__ __launch_bounds__(256) void k_scan1(const float* __restrict__ delta,
    const float* __restrict__ u, const float* __restrict__ xdbl,
    const float* __restrict__ A_logs, float* __restrict__ aprod_o,
    float* __restrict__ hacc_o) {
  int gid = blockIdx.x;
  int dg = gid % 24;
  int ck = (gid / 24) % CHn;
  int b = gid / (24 * CHn);
  int tid = threadIdx.x;
  int n = tid & 15;
  int d = dg * 16 + (tid >> 4);
  float Av = -expf(A_logs[d * NSTn + n]);
  const float* dp = delta + ((size_t)b * Dn + d) * Ln + ck * LCn;
  const float* up = u + ((size_t)b * Dn + d) * Ln + ck * LCn;
  const float* bp = xdbl + ((size_t)b * 56 + 24 + n) * Ln + ck * LCn;
  float ap = 1.f, hc = 0.f;
  for (int t = 0; t < LCn; t += 4) {
    float4 d4 = *(const float4*)(dp + t);
    float4 u4 = *(const float4*)(up + t);
    float4 b4 = *(const float4*)(bp + t);
    float dv[4] = {d4.x, d4.y, d4.z, d4.w};
    float uv[4] = {u4.x, u4.y, u4.z, u4.w};
    float bv[4] = {b4.x, b4.y, b4.z, b4.w};
#pragma unroll
    for (int q = 0; q < 4; ++q) {
      float a = __expf(dv[q] * Av);
      hc = hc * a + dv[q] * uv[q] * bv[q];
      ap *= a;
    }
  }
  size_t o = ((size_t)(b * CHn + ck) * Dn + dg * 16) * NSTn + tid;
  aprod_o[o] = ap;
  hacc_o[o] = hc;
}

// ---------------- scan phase 2: combine chunks sequentially (CHn steps)
__global__ __launch_bounds__(256) void k_scan2(const float* __restrict__ aprod,
    const float* __restrict__ hacc, float* __restrict__ hstart) {
  int gid = blockIdx.x * 256 + threadIdx.x;  // over B*D*NST
  int b = gid / (Dn * NSTn);
  int dn = gid % (Dn * NSTn);
  float h = 0.f;
  for (int k = 0; k < CHn; ++k) {
    size_t o = (size_t)(b * CHn + k) * Dn * NSTn + dn;
    hstart[o] = h;
    h = h * aprod[o] + hacc[o];
  }
}

// ---------------- scan phase 3: replay with h_start, emit y (+Ds*u) in (B,D,L)
// thread = (d, n4); 4 states per thread; n-reduce = 3 in-register FMAs + 2 quad shuffles (DPP)
__global__ __launch_bounds__(256) void k_scan3(const float* __restrict__ delta,
    const float* __restrict__ u, const float* __restrict__ xdbl,
    const float* __restrict__ A_logs, const float* __restrict__ Ds,
    const float* __restrict__ hstart, float* __restrict__ ys) {
  int gid = blockIdx.x;
  int dg = gid % 6;
  int ck = (gid / 6) % CHn;
  int b = gid / (6 * CHn);
  int tid = threadIdx.x;
  int n4 = tid & 3;
  int dloc = tid >> 2;  // 0..63
  int d = dg * 64 + dloc;
  float Av[4], h[4];
#pragma unroll
  for (int k = 0; k < 4; ++k) Av[k] = -expf(A_logs[d * NSTn + n4 + 4 * k]);
  float Dv = Ds[d];
  const float* dp = delta + ((size_t)b * Dn + d) * Ln + ck * LCn;
  const float* up = u + ((size_t)b * Dn + d) * Ln + ck * LCn;
  const float* bp = xdbl + ((size_t)b * 56 + 24 + n4) * Ln + ck * LCn;
  const float* cp = xdbl + ((size_t)b * 56 + 40 + n4) * Ln + ck * LCn;
  const float* hsp = hstart + ((size_t)(b * CHn + ck) * Dn + d) * NSTn;
#pragma unroll
  for (int k = 0; k < 4; ++k) h[k] = hsp[n4 + 4 * k];
  float* yp = ys + ((size_t)b * Dn + d) * Ln + ck * LCn;
  for (int t = 0; t < LCn; t += 4) {
    float4 d4 = *(const float4*)(dp + t);
    float4 u4 = *(const float4*)(up + t);
    float bv[4][4], cv[4][4];
#pragma unroll
    for (int k = 0; k < 4; ++k) {
      float4 bb = *(const float4*)(bp + (size_t)(4 * k) * Ln + t);
      float4 cc = *(const float4*)(cp + (size_t)(4 * k) * Ln + t);
      bv[k][0] = bb.x; bv[k][1] = bb.y; bv[k][2] = bb.z; bv[k][3] = bb.w;
      cv[k][0] = cc.x; cv[k][1] = cc.y; cv[k][2] = cc.z; cv[k][3] = cc.w;
    }
    float dv[4] = {d4.x, d4.y, d4.z, d4.w};
    float uv[4] = {u4.x, u4.y, u4.z, u4.w};
    float y4[4];
#pragma unroll
    for (int q = 0; q < 4; ++q) {
      float du = dv[q] * uv[q];
      float p = 0.f;
#pragma unroll
      for (int k = 0; k < 4; ++k) {
        float a = __expf(dv[q] * Av[k]);
        h[k] = h[k] * a + du * bv[k][q];
        p += h[k] * cv[k][q];
      }
      p += __shfl_xor(p, 1, 4);  // quad_perm DPP: VALU pipe, no LDS
      p += __shfl_xor(p, 2, 4);
      y4[q] = p + Dv * uv[q];
    }
    if (n4 == 0) {
      float4 o4; o4.x = y4[0]; o4.y = y4[1]; o4.z = y4[2]; o4.w = y4[3];
      *(float4*)(yp + t) = o4;
    }
  }
}

// ---------------- LN stats per sorted token: mu, rsigma  (ys in (B,D,L))
__global__ __launch_bounds__(256) void k_ln(const float* __restrict__ ys,
    float* __restrict__ mu_o, float* __restrict__ rs_o) {
  int b = blockIdx.x >> 6;
  int i0 = (blockIdx.x & 63) << 6;
  int t = threadIdx.x & 63;
  int q = threadIdx.x >> 6;
  int i = i0 + t;
  const float* p = ys + ((size_t)b * Dn + q * 96) * Ln + i;
  float s = 0.f, sq = 0.f;
  for (int d = 0; d < 96; d += 2) {
    float v0 = p[(size_t)d * Ln];
    float v1 = p[(size_t)(d + 1) * Ln];
    s += v0 + v1;
    sq += v0 * v0 + v1 * v1;
  }
  __shared__ float sh_s[4][64], sh_q[4][64];
  sh_s[q][t] = s;
  sh_q[q][t] = sq;
  __syncthreads();
  if (q == 0) {
    float ts = s + sh_s[1][t] + sh_s[2][t] + sh_s[3][t];
    float tq = sq + sh_q[1][t] + sh_q[2][t] + sh_q[3][t];
    float mu = ts * (1.f / Dn);
    float var = tq * (1.f / Dn) - mu * mu;
    mu_o[b * Ln + i] = mu;
    rs_o[b * Ln + i] = rsqrtf(var + 1e-5f);
  }
}

// ---------------- fused normalize + out projection (sorted domain), register-blocked
__global__ __launch_bounds__(256) void k_outproj(const float* __restrict__ ys,
    const float* __restrict__ mu_v, const float* __restrict__ rs_v,
    const float* __restrict__ ln_g, const float* __restrict__ ln_b,
    const float* __restrict__ out_wT, const float* __restrict__ out_b,
    float* __restrict__ outs) {
  int gid = blockIdx.x;
  int g = gid % 6;
  int lt = (gid / 6) % 16;
  int b = gid / 96;
  int i = lt * 256 + threadIdx.x;
  int c0 = g * 32;
  const float* yp = ys + (size_t)b * Dn * Ln + i;
  float mu = mu_v[b * Ln + i], rs = rs_v[b * Ln + i];
  float acc[32];
#pragma unroll
  for (int j = 0; j < 32; ++j) acc[j] = out_b[c0 + j];
  for (int d = 0; d < Dn; d += 4) {
    float yv[4];
#pragma unroll
    for (int k = 0; k < 4; ++k) yv[k] = yp[(size_t)(d + k) * Ln];
#pragma unroll
    for (int k = 0; k < 4; ++k) {
      float v = (yv[k] - mu) * rs * ln_g[d + k] + ln_b[d + k];
      const float* wr = out_wT + (d + k) * Cn + c0;
#pragma unroll
      for (int j = 0; j < 32; ++j) acc[j] += wr[j] * v;
    }
  }
  float* op = outs + ((size_t)b * Ln + i) * Cn + c0;
#pragma unroll
  for (int j = 0; j < 32; ++j) op[j] = acc[j];
}

// ---------------- inverse-permute + transpose to (B, C, L)
__global__ __launch_bounds__(256) void k_perm(const float* __restrict__ outs,
    const int* __restrict__ iidx, float* __restrict__ out) {
  int b = blockIdx.x >> 6;
  int lt = blockIdx.x & 63;
  int l0 = lt * 64;
  __shared__ float ot[64][Cn + 1];
  __shared__ int ivs[64];
  if (threadIdx.x < 64) ivs[threadIdx.x] = iidx[(size_t)b * Ln + l0 + threadIdx.x];
  __syncthreads();
  for (int e = threadIdx.x; e < 3072; e += 256) {
    int ii = e / 48;
    int qq = (e % 48) * 4;
    const float* sp = outs + ((size_t)b * Ln + ivs[ii]) * Cn + qq;
    float4 vv = *(const float4*)sp;
    ot[ii][qq] = vv.x;
    ot[ii][qq + 1] = vv.y;
    ot[ii][qq + 2] = vv.z;
    ot[ii][qq + 3] = vv.w;
  }
  __syncthreads();
  for (int e = threadIdx.x; e < 64 * Cn; e += 256) {
    int c = e >> 6;
    int ii = e & 63;
    out[((size_t)b * Cn + c) * Ln + l0 + ii] = ot[ii][c];
  }
}

extern "C" void kernel_launch(void* const* d_in, const int* in_sizes, int n_in,
                              void* d_out, int out_size, void* d_ws, size_t ws_size,
                              hipStream_t stream) {
  (void)in_sizes; (void)n_in; (void)out_size; (void)ws_size;
  const float* x = (const float*)d_in[0];
  const float* gumbel = (const float*)d_in[1];
  const float* emb_B = (const float*)d_in[2];
  const float* emb_A = (const float*)d_in[3];
  const float* route_w1 = (const float*)d_in[4];
  const float* route_b1 = (const float*)d_in[5];
  const float* route_w2 = (const float*)d_in[6];
  const float* route_b2 = (const float*)d_in[7];
  const float* in_proj_w = (const float*)d_in[8];
  const float* in_proj_b = (const float*)d_in[9];
  const float* cpe_w = (const float*)d_in[10];
  const float* cpe_b = (const float*)d_in[11];
  const float* x_proj_w = (const float*)d_in[12];
  const float* dt_w = (const float*)d_in[13];
  const float* dt_b = (const float*)d_in[14];
  const float* A_logs = (const float*)d_in[15];
  const float* Ds = (const float*)d_in[16];
  const float* ln_g = (const float*)d_in[17];
  const float* ln_b = (const float*)d_in[18];
  const float* out_w = (const float*)d_in[19];
  const float* out_b = (const float*)d_in[20];

  float* ws = (float*)d_ws;
  float* v0 = ws;                     // 12582912 (later ys, (B,D,L))
  float* v = v0 + 12582912;           // 12582912 (cpe out; dead after gather ->
                                      //   aliased by ap/hc/hs; later outs)
  float* u = v + 12582912;            // 12582912
  float* dl = u + 12582912;           // 12582912
  float* xd = dl + 12582912;          // 1835008
  float* fe = xd + 1835008;           // 1024
  float* owT = fe + 1024;             // 73728
  float* xpT = owT + 73728;           // 21504
  int* idxp = (int*)(xpT + 21504);    // 32768
  int* sidx = idxp + 32768;           // 32768
  int* iidx = sidx + 32768;           // 32768
  float* muv = (float*)(iidx + 32768);// 32768
  float* rsv = muv + 32768;           // 32768
  // scan scratch aliases the dead cpe buffer (v): 3 x 1572864 = 4.7M < 12.58M
  float* ap = v;
  float* hc = ap + 1572864;
  float* hs = hc + 1572864;

  k_prep<<<288, 256, 0, stream>>>(emb_B, emb_A, x_proj_w, out_w, fe, xpT, owT);
  k_route<<<128, 256, 0, stream>>>(x, gumbel, route_w1, route_b1, route_w2, route_b2, idxp);
  k_sort<<<8, 64, 0, stream>>>(idxp, sidx, iidx);
  k_inproj<<<1536, 256, 0, stream>>>(x, in_proj_w, in_proj_b, v0);
  k_cpe<<<Bn * Dn, 256, 0, stream>>>(v0, cpe_w, cpe_b, v);
  k_gather<<<512, 256, 0, stream>>>(v, sidx, u);
  k_xdbl<<<512, 256, 0, stream>>>(u, xpT, fe, idxp, xd);
  k_delta<<<1536, 256, 0, stream>>>(xd, dt_w, dt_b, dl);
  k_scan1<<<24 * CHn * Bn, 256, 0, stream>>>(dl, u, xd, A_logs, ap, hc);
  k_scan2<<<192, 256, 0, stream>>>(ap, hc, hs);
  k_scan3<<<6 * CHn * Bn, 256, 0, stream>>>(dl, u, xd, A_logs, Ds, hs, v0);
  k_ln<<<512, 256, 0, stream>>>(v0, muv, rsv);
  k_outproj<<<768, 256, 0, stream>>>(v0, muv, rsv, ln_g, ln_b, owT, out_b, v);
  k_perm<<<512, 256, 0, stream>>>(v, iidx, (float*)d_out);
}